// Round 10
// baseline (859.169 us; speedup 1.0000x reference)
//
#include <hip/hip_runtime.h>
#include <math.h>

typedef _Float16 f16_t;
typedef f16_t f16x8 __attribute__((ext_vector_type(8)));
typedef f16_t f16x4 __attribute__((ext_vector_type(4)));
typedef float f32x4 __attribute__((ext_vector_type(4)));
typedef float fv4 __attribute__((ext_vector_type(4)));

#define MFMA16(a, b, c) __builtin_amdgcn_mfma_f32_16x16x32_f16(a, b, c, 0, 0, 0)

__device__ __forceinline__ void gload16(const void* g, void* l) {
  __builtin_amdgcn_global_load_lds((const __attribute__((address_space(1))) void*)g,
                                   (__attribute__((address_space(3))) void*)l, 16, 0, 0);
}

// ---------------------------------------------------------------------------
// Fused LayerNorm (fp32 -> f16) + LoRA-kv first stage.
// One 256-thread block per row: y = LN(x), t_k[row] = y @ la_k^T,
// t_v[row] = y @ la_v^T (computed from the f32 y -- more accurate than f16).
// ---------------------------------------------------------------------------
__global__ __launch_bounds__(256) void ln_lora_f32(
    const float* __restrict__ x, const float* __restrict__ g,
    const float* __restrict__ b, const float* __restrict__ la_k,
    const float* __restrict__ la_v, f16_t* __restrict__ y,
    float* __restrict__ t_k, float* __restrict__ t_v) {
  const int D = 1024;
  int row = blockIdx.x;
  int t = threadIdx.x;
  const float* xr = x + (size_t)row * D + t * 4;
  float x0 = xr[0], x1 = xr[1], x2 = xr[2], x3 = xr[3];
  float sum = x0 + x1 + x2 + x3;
  float sq = x0 * x0 + x1 * x1 + x2 * x2 + x3 * x3;
  for (int d = 32; d; d >>= 1) {
    sum += __shfl_down(sum, d);
    sq += __shfl_down(sq, d);
  }
  __shared__ float ssum[4], ssq[4];
  __shared__ float red[4][8];
  int w = t >> 6, lane = t & 63;
  if (lane == 0) { ssum[w] = sum; ssq[w] = sq; }
  __syncthreads();
  float ts = ssum[0] + ssum[1] + ssum[2] + ssum[3];
  float tq = ssq[0] + ssq[1] + ssq[2] + ssq[3];
  float mean = ts * (1.0f / 1024.0f);
  float var = tq * (1.0f / 1024.0f) - mean * mean;
  float rstd = rsqrtf(var + 1e-5f);
  const float* gr = g + t * 4;
  const float* br = b + t * 4;
  float y0 = (x0 - mean) * rstd * gr[0] + br[0];
  float y1 = (x1 - mean) * rstd * gr[1] + br[1];
  float y2 = (x2 - mean) * rstd * gr[2] + br[2];
  float y3 = (x3 - mean) * rstd * gr[3] + br[3];
  f16_t* yr = y + (size_t)row * D + t * 4;
  yr[0] = (f16_t)y0; yr[1] = (f16_t)y1; yr[2] = (f16_t)y2; yr[3] = (f16_t)y3;
  // LoRA-kv dots: a[0..3] = k-rows, a[4..7] = v-rows
  float a[8];
#pragma unroll
  for (int r = 0; r < 4; ++r) {
    const float* kr = la_k + (size_t)r * D + t * 4;
    const float* vr = la_v + (size_t)r * D + t * 4;
    a[r] = y0 * kr[0] + y1 * kr[1] + y2 * kr[2] + y3 * kr[3];
    a[4 + r] = y0 * vr[0] + y1 * vr[1] + y2 * vr[2] + y3 * vr[3];
  }
#pragma unroll
  for (int i = 0; i < 8; ++i)
    for (int d = 32; d; d >>= 1) a[i] += __shfl_down(a[i], d);
  if (lane == 0) {
#pragma unroll
    for (int i = 0; i < 8; ++i) red[w][i] = a[i];
  }
  __syncthreads();
  if (t < 8) {
    float s = red[0][t] + red[1][t] + red[2][t] + red[3][t];
    if (t < 4) t_k[(size_t)row * 4 + t] = s;
    else t_v[(size_t)row * 4 + (t - 4)] = s;
  }
}

// LayerNorm, f16 input -> f16 output.
__global__ __launch_bounds__(256) void ln_f16(const f16_t* __restrict__ x,
                                              const float* __restrict__ g,
                                              const float* __restrict__ b,
                                              f16_t* __restrict__ y) {
  const int D = 1024;
  int row = blockIdx.x;
  int t = threadIdx.x;
  const f16_t* xr = x + (size_t)row * D + t * 4;
  float x0 = (float)xr[0], x1 = (float)xr[1], x2 = (float)xr[2], x3 = (float)xr[3];
  float sum = x0 + x1 + x2 + x3;
  float sq = x0 * x0 + x1 * x1 + x2 * x2 + x3 * x3;
  for (int d = 32; d; d >>= 1) {
    sum += __shfl_down(sum, d);
    sq += __shfl_down(sq, d);
  }
  __shared__ float ssum[4], ssq[4];
  int w = t >> 6, lane = t & 63;
  if (lane == 0) { ssum[w] = sum; ssq[w] = sq; }
  __syncthreads();
  float ts = ssum[0] + ssum[1] + ssum[2] + ssum[3];
  float tq = ssq[0] + ssq[1] + ssq[2] + ssq[3];
  float mean = ts * (1.0f / 1024.0f);
  float var = tq * (1.0f / 1024.0f) - mean * mean;
  float rstd = rsqrtf(var + 1e-5f);
  f16_t* yr = y + (size_t)row * D + t * 4;
  const float* gr = g + t * 4;
  const float* br = b + t * 4;
  yr[0] = (f16_t)((x0 - mean) * rstd * gr[0] + br[0]);
  yr[1] = (f16_t)((x1 - mean) * rstd * gr[1] + br[1]);
  yr[2] = (f16_t)((x2 - mean) * rstd * gr[2] + br[2]);
  yr[3] = (f16_t)((x3 - mean) * rstd * gr[3] + br[3]);
}

// ---------------------------------------------------------------------------
// Weight convert fp32 -> f16, one fused launch for all 6 matrices.
// (q/k/v write into one contiguous [3072,1024] blob via the o* pointers.)
// ---------------------------------------------------------------------------
__global__ __launch_bounds__(256) void convert_w(
    const float* __restrict__ wq, const float* __restrict__ wk,
    const float* __restrict__ wv, const float* __restrict__ wo,
    const float* __restrict__ w1, const float* __restrict__ w2,
    f16_t* __restrict__ oq, f16_t* __restrict__ ok, f16_t* __restrict__ ov,
    f16_t* __restrict__ oo, f16_t* __restrict__ o1, f16_t* __restrict__ o2) {
  int bid = blockIdx.x;
  const float* src;
  f16_t* dst;
  int bi;
  if (bid < 2048) {
    int seg = bid >> 9;
    bi = bid & 511;
    src = seg == 0 ? wq : seg == 1 ? wk : seg == 2 ? wv : wo;
    dst = seg == 0 ? oq : seg == 1 ? ok : seg == 2 ? ov : oo;
  } else if (bid < 4096) {
    bi = bid - 2048; src = w1; dst = o1;
  } else {
    bi = bid - 4096; src = w2; dst = o2;
  }
  size_t idx = (size_t)bi * 2048 + (size_t)threadIdx.x * 8;
  fv4 a = *(const fv4*)(src + idx);
  fv4 b = *(const fv4*)(src + idx + 4);
  f16x8 h;
#pragma unroll
  for (int j = 0; j < 4; ++j) { h[j] = (f16_t)a[j]; h[4 + j] = (f16_t)b[j]; }
  *(f16x8*)(dst + idx) = h;
}

// LoRA first stage, single matrix (o-projection).
__global__ __launch_bounds__(256) void lora_t_kernel(const f16_t* __restrict__ h,
                                                     const float* __restrict__ la,
                                                     float* __restrict__ t, int K) {
  int lane = threadIdx.x & 63;
  int w = threadIdx.x >> 6;
  int row = blockIdx.x * 4 + w;
  const f16_t* hrow = h + (size_t)row * K;
  float acc[4] = {0.f, 0.f, 0.f, 0.f};
  for (int it = 0; it < K / 512; ++it) {
    int base = it * 512 + lane * 8;
    f16x8 hx = *(const f16x8*)(hrow + base);
#pragma unroll
    for (int r = 0; r < 4; ++r) {
      const float* ar = la + (size_t)r * K + base;
#pragma unroll
      for (int j = 0; j < 8; ++j) acc[r] += (float)hx[j] * ar[j];
    }
  }
#pragma unroll
  for (int r = 0; r < 4; ++r) {
    for (int d = 32; d; d >>= 1) acc[r] += __shfl_down(acc[r], d);
  }
  if (lane == 0) {
#pragma unroll
    for (int r = 0; r < 4; ++r) t[(size_t)row * 4 + r] = acc[r];
  }
}

// ===========================================================================
// PIPELINED MFMA f16 GEMM core (unchanged from R8, +5% proven): 128x256 tile,
// BK=64, 512 threads, 3-deep LDS (144 KB), counted-vmcnt pipeline.
// ===========================================================================
#define GEMM_PIPE_BODY                                                        \
  f32x4 acc[4][4];                                                            \
  _Pragma("unroll") for (int i = 0; i < 4; ++i)                               \
      _Pragma("unroll") for (int j = 0; j < 4; ++j)                           \
          acc[i][j] = (f32x4){0.f, 0.f, 0.f, 0.f};                            \
  const int nsteps = K >> 6;                                                  \
  stageA(0, 0); stageB(0, 0);                                                 \
  stageA(1, 1); stageB(1, 1);                                                 \
  stageA(2, 2); stageB(2, 2);                                                 \
  int b3 = 0;                                                                 \
  for (int kt = 0; kt < nsteps; ++kt) {                                       \
    if (kt + 2 < nsteps)                                                      \
      asm volatile("s_waitcnt vmcnt(12)" ::: "memory");                       \
    else if (kt + 1 < nsteps)                                                 \
      asm volatile("s_waitcnt vmcnt(6)" ::: "memory");                        \
    else                                                                      \
      asm volatile("s_waitcnt vmcnt(0)" ::: "memory");                        \
    __builtin_amdgcn_sched_barrier(0);                                        \
    __builtin_amdgcn_s_barrier();                                             \
    f16x8 af[4][2], bf[4][2];                                                 \
    _Pragma("unroll") for (int kk = 0; kk < 2; ++kk) {                        \
      _Pragma("unroll") for (int i = 0; i < 4; ++i) {                         \
        int row = wm * 64 + i * 16 + l15;                                     \
        af[i][kk] = *(const f16x8*)((const char*)Abuf[b3] + row * 128 +       \
                                    ((kk * 64 + lhi * 16) ^ ((row & 7) << 4)));\
      }                                                                       \
      _Pragma("unroll") for (int j = 0; j < 4; ++j) {                         \
        int row = wn * 64 + j * 16 + l15;                                     \
        bf[j][kk] = *(const f16x8*)((const char*)Bbuf[b3] + row * 128 +       \
                                    ((kk * 64 + lhi * 16) ^ ((row & 7) << 4)));\
      }                                                                       \
    }                                                                         \
    asm volatile("s_waitcnt lgkmcnt(0)" ::: "memory");                        \
    __builtin_amdgcn_sched_barrier(0);                                        \
    __builtin_amdgcn_s_barrier();                                             \
    if (kt + 3 < nsteps) { stageA(kt + 3, b3); stageB(kt + 3, b3); }          \
    __builtin_amdgcn_sched_barrier(0);                                        \
    __builtin_amdgcn_s_setprio(1);                                            \
    _Pragma("unroll") for (int kk = 0; kk < 2; ++kk)                          \
        _Pragma("unroll") for (int i = 0; i < 4; ++i)                         \
            _Pragma("unroll") for (int j = 0; j < 4; ++j)                     \
                acc[i][j] = MFMA16(af[i][kk], bf[j][kk], acc[i][j]);          \
    __builtin_amdgcn_s_setprio(0);                                            \
    b3 = (b3 == 2) ? 0 : b3 + 1;                                              \
  }

// ---------------------------------------------------------------------------
// Pipelined GEMM with generic epilogue.
// ---------------------------------------------------------------------------
__global__ __launch_bounds__(512, 2) void gemm_pipe(
    const f16_t* __restrict__ A, const f16_t* __restrict__ B,
    const float* __restrict__ bias, const float* __restrict__ loraT,
    const float* __restrict__ loraB, const float* residf,
    const f16_t* __restrict__ residb, f16_t* Cb, float* Cf,
    int M, int N, int K, int ldb, int dogelu) {
  __shared__ __align__(16) f16_t Abuf[3][8192];
  __shared__ __align__(16) f16_t Bbuf[3][16384];
  const int tid = threadIdx.x;
  const int lane = tid & 63, wid = tid >> 6;
  const int wm = wid >> 2, wn = wid & 3;
  const int l15 = lane & 15, lhi = lane >> 4;
  int nwg = gridDim.x * gridDim.y;
  int bid = blockIdx.y * gridDim.x + blockIdx.x;
  int swz = (bid & 7) * (nwg >> 3) + (bid >> 3);
  const int m0 = (swz / gridDim.x) * 128, n0 = (swz % gridDim.x) * 256;
  const int arow = tid >> 3;
  const int aslot = tid & 7;

  auto stageA = [&](int step, int buf) {
#pragma unroll
    for (int c = 0; c < 2; ++c) {
      int r = c * 64 + arow;
      int cm = aslot ^ (r & 7);
      gload16(A + (size_t)(m0 + r) * K + (size_t)step * 64 + cm * 8,
              (char*)Abuf[buf] + c * 8192 + wid * 1024);
    }
  };
  auto stageB = [&](int step, int buf) {
#pragma unroll
    for (int c = 0; c < 4; ++c) {
      int r = c * 64 + arow;
      int cm = aslot ^ (r & 7);
      gload16(B + (size_t)(n0 + r) * ldb + (size_t)step * 64 + cm * 8,
              (char*)Bbuf[buf] + c * 8192 + wid * 1024);
    }
  };

  GEMM_PIPE_BODY

  const int gm = m0 + wm * 64, gn = n0 + wn * 64;
#pragma unroll
  for (int j = 0; j < 4; ++j) {
    int gcol = gn + j * 16 + l15;
    float bj = bias ? bias[gcol] : 0.f;
    float lb0 = 0.f, lb1 = 0.f, lb2 = 0.f, lb3 = 0.f;
    if (loraB) {
      const float* p = loraB + (size_t)gcol * 4;
      lb0 = p[0]; lb1 = p[1]; lb2 = p[2]; lb3 = p[3];
    }
#pragma unroll
    for (int i = 0; i < 4; ++i) {
      float v4[4];
#pragma unroll
      for (int r = 0; r < 4; ++r) {
        int grow = gm + i * 16 + lhi * 4 + r;
        float val = acc[i][j][r] + bj;
        if (loraT) {
          const float* tp = loraT + (size_t)grow * 4;
          val += 0.25f * (tp[0] * lb0 + tp[1] * lb1 + tp[2] * lb2 + tp[3] * lb3);
        }
        if (dogelu) val = 0.5f * val * (1.0f + erff(val * 0.70710678118654752f));
        if (residf) val += residf[(size_t)grow * N + gcol];
        if (residb) val += (float)residb[(size_t)grow * N + gcol];
        v4[r] = val;
      }
      if (Cf) {
#pragma unroll
        for (int r = 0; r < 4; ++r)
          Cf[(size_t)(gm + i * 16 + lhi * 4 + r) * N + gcol] = v4[r];
      } else {
#pragma unroll
        for (int r = 0; r < 4; ++r)
          Cb[(size_t)(gm + i * 16 + lhi * 4 + r) * N + gcol] = (f16_t)v4[r];
      }
    }
  }
}

// ---------------------------------------------------------------------------
// Pipelined fused QKV GEMM (unchanged from R8).
// ---------------------------------------------------------------------------
__global__ __launch_bounds__(512, 2) void gemm_qkv_pipe(
    const f16_t* __restrict__ A, const f16_t* __restrict__ W,
    const float* __restrict__ bq, const float* __restrict__ bv,
    const float* __restrict__ t_k, const float* __restrict__ lb_k,
    const float* __restrict__ t_v, const float* __restrict__ lb_v,
    f16_t* __restrict__ Pq, f16_t* __restrict__ Pk, f16_t* __restrict__ Pvt,
    int K) {
  const int D = 1024;
  __shared__ __align__(16) f16_t Abuf[3][8192];
  __shared__ __align__(16) f16_t Bbuf[3][16384];
  const int tid = threadIdx.x;
  const int lane = tid & 63, wid = tid >> 6;
  const int wm = wid >> 2, wn = wid & 3;
  const int l15 = lane & 15, lhi = lane >> 4;
  int nwg = gridDim.x * gridDim.y;
  int bid = blockIdx.y * gridDim.x + blockIdx.x;
  int swz = (bid & 7) * (nwg >> 3) + (bid >> 3);
  const int m0 = (swz / gridDim.x) * 128, n0 = (swz % gridDim.x) * 256;
  const int seg = n0 >> 10;
  const int arow = tid >> 3;
  const int aslot = tid & 7;

  auto stageA = [&](int step, int buf) {
#pragma unroll
    for (int c = 0; c < 2; ++c) {
      int r = c * 64 + arow;
      int cm = aslot ^ (r & 7);
      gload16(A + (size_t)(m0 + r) * K + (size_t)step * 64 + cm * 8,
              (char*)Abuf[buf] + c * 8192 + wid * 1024);
    }
  };
  auto stageB = [&](int step, int buf) {
#pragma unroll
    for (int c = 0; c < 4; ++c) {
      int r = c * 64 + arow;
      int cm = aslot ^ (r & 7);
      gload16(W + (size_t)(n0 + r) * K + (size_t)step * 64 + cm * 8,
              (char*)Bbuf[buf] + c * 8192 + wid * 1024);
    }
  };

  GEMM_PIPE_BODY

  const int gm = m0 + wm * 64, gn = n0 + wn * 64;
  const float* tB = (seg == 1) ? t_k : t_v;
#pragma unroll
  for (int j = 0; j < 4; ++j) {
    int gcol = gn + j * 16 + l15;
    int c = gcol & 1023;
    float bj = (seg == 0) ? bq[c] : (seg == 2 ? bv[c] : 0.f);
    float lb0 = 0.f, lb1 = 0.f, lb2 = 0.f, lb3 = 0.f;
    if (seg) {
      const float* p = (seg == 1 ? lb_k : lb_v) + (size_t)c * 4;
      lb0 = p[0]; lb1 = p[1]; lb2 = p[2]; lb3 = p[3];
    }
#pragma unroll
    for (int i = 0; i < 4; ++i) {
      float v4[4];
#pragma unroll
      for (int r = 0; r < 4; ++r) {
        int grow = gm + i * 16 + lhi * 4 + r;
        float val = acc[i][j][r] + bj;
        if (seg) {
          const float* tp = tB + (size_t)grow * 4;
          val += 0.25f * (tp[0] * lb0 + tp[1] * lb1 + tp[2] * lb2 + tp[3] * lb3);
        }
        v4[r] = val;
      }
      if (seg < 2) {
        f16_t* dst = (seg == 0) ? Pq : Pk;
#pragma unroll
        for (int r = 0; r < 4; ++r)
          dst[(size_t)(gm + i * 16 + lhi * 4 + r) * D + c] = (f16_t)v4[r];
      } else {
        int grow0 = gm + i * 16 + lhi * 4;
        int bb = grow0 >> 10, ss = grow0 & 1023;
        int hh = c >> 6, dd = c & 63;
        f16x4 pk;
#pragma unroll
        for (int r = 0; r < 4; ++r) pk[r] = (f16_t)v4[r];
        *(f16x4*)(Pvt + (((size_t)bb * 16 + hh) * 64 + dd) * 1024 + ss) = pk;
      }
    }
  }
}

// ---------------------------------------------------------------------------
// Fallback GEMM (B fp32, reg-staged + converted); used only when ws_size
// can't hold f16 weights. Full epilogue incl. transposed-V output.
// ---------------------------------------------------------------------------
__global__ __launch_bounds__(256, 2) void gemm_mfma(
    const f16_t* __restrict__ A, const float* __restrict__ B,
    const float* __restrict__ bias, const float* __restrict__ loraT,
    const float* __restrict__ loraB, const float* residf,
    const f16_t* __restrict__ residb, f16_t* Cb, float* Cf, f16_t* Cvt,
    int M, int N, int K, int ldb, int dogelu) {
  __shared__ __align__(16) f16_t smem[2][16384];
  const int tid = threadIdx.x;
  const int lane = tid & 63, wid = tid >> 6;
  const int wm = wid >> 1, wn = wid & 1;
  const int l15 = lane & 15, lhi = lane >> 4;
  const int m0 = blockIdx.y * 128, n0 = blockIdx.x * 128;
  const int arow = tid >> 3;
  const int aslot = tid & 7;

  f32x4 acc[4][4];
#pragma unroll
  for (int i = 0; i < 4; ++i)
#pragma unroll
    for (int j = 0; j < 4; ++j) acc[i][j] = (f32x4){0.f, 0.f, 0.f, 0.f};

  fv4 breg[4][2];

  auto stageA = [&](int step, int buf) {
#pragma unroll
    for (int c = 0; c < 4; ++c) {
      int r = c * 32 + arow;
      int cm = aslot ^ (r & 7);
      gload16(A + (size_t)(m0 + r) * K + (size_t)step * 64 + cm * 8,
              (char*)&smem[buf][0] + c * 4096 + wid * 1024);
    }
  };
  auto loadB = [&](int step) {
#pragma unroll
    for (int c = 0; c < 4; ++c) {
      int r = c * 32 + arow;
      const float* gp = B + (size_t)(n0 + r) * ldb + (size_t)step * 64 + aslot * 8;
      breg[c][0] = *(const fv4*)gp;
      breg[c][1] = *(const fv4*)(gp + 4);
    }
  };
  auto writeB = [&](int buf) {
#pragma unroll
    for (int c = 0; c < 4; ++c) {
      int r = c * 32 + arow;
      f16x8 hh;
#pragma unroll
      for (int j = 0; j < 4; ++j) hh[j] = (f16_t)breg[c][0][j];
#pragma unroll
      for (int j = 0; j < 4; ++j) hh[4 + j] = (f16_t)breg[c][1][j];
      int boff = r * 128 + ((aslot * 16) ^ ((r & 7) << 4));
      *(f16x8*)((char*)&smem[buf][8192] + boff) = hh;
    }
  };

  const int nsteps = K >> 6;
  stageA(0, 0);
  loadB(0);
  writeB(0);
  __syncthreads();
  for (int t = 0; t < nsteps; ++t) {
    int cur = t & 1, nxt = cur ^ 1;
    if (t + 1 < nsteps) { stageA(t + 1, nxt); loadB(t + 1); }
    const char* As = (const char*)&smem[cur][0];
    const char* Bs = (const char*)&smem[cur][8192];
#pragma unroll
    for (int kk = 0; kk < 2; ++kk) {
      f16x8 af[4], bf[4];
#pragma unroll
      for (int i = 0; i < 4; ++i) {
        int row = wm * 64 + i * 16 + l15;
        af[i] = *(const f16x8*)(As + row * 128 + ((kk * 64 + lhi * 16) ^ ((row & 7) << 4)));
      }
#pragma unroll
      for (int j = 0; j < 4; ++j) {
        int row = wn * 64 + j * 16 + l15;
        bf[j] = *(const f16x8*)(Bs + row * 128 + ((kk * 64 + lhi * 16) ^ ((row & 7) << 4)));
      }
#pragma unroll
      for (int i = 0; i < 4; ++i)
#pragma unroll
        for (int j = 0; j < 4; ++j) acc[i][j] = MFMA16(af[i], bf[j], acc[i][j]);
    }
    if (t + 1 < nsteps) writeB(nxt);
    __syncthreads();
  }

  const int gm = m0 + wm * 64, gn = n0 + wn * 64;
#pragma unroll
  for (int j = 0; j < 4; ++j) {
    int gcol = gn + j * 16 + l15;
    float bj = bias ? bias[gcol] : 0.f;
    float lb0 = 0.f, lb1 = 0.f, lb2 = 0.f, lb3 = 0.f;
    if (loraB) {
      const float* p = loraB + (size_t)gcol * 4;
      lb0 = p[0]; lb1 = p[1]; lb2 = p[2]; lb3 = p[3];
    }
#pragma unroll
    for (int i = 0; i < 4; ++i) {
      float v4[4];
#pragma unroll
      for (int r = 0; r < 4; ++r) {
        int grow = gm + i * 16 + lhi * 4 + r;
        float val = acc[i][j][r] + bj;
        if (loraT) {
          const float* tp = loraT + (size_t)grow * 4;
          val += 0.25f * (tp[0] * lb0 + tp[1] * lb1 + tp[2] * lb2 + tp[3] * lb3);
        }
        if (dogelu) val = 0.5f * val * (1.0f + erff(val * 0.70710678118654752f));
        if (residf) val += residf[(size_t)grow * N + gcol];
        if (residb) val += (float)residb[(size_t)grow * N + gcol];
        v4[r] = val;
      }
      if (Cf) {
#pragma unroll
        for (int r = 0; r < 4; ++r)
          Cf[(size_t)(gm + i * 16 + lhi * 4 + r) * N + gcol] = v4[r];
      } else if (Cvt) {
        int grow0 = gm + i * 16 + lhi * 4;
        int bb = grow0 >> 10, ss = grow0 & 1023;
        int hh = gcol >> 6, dd = gcol & 63;
        f16x4 pk;
#pragma unroll
        for (int r = 0; r < 4; ++r) pk[r] = (f16_t)v4[r];
        *(f16x4*)(Cvt + (((size_t)bb * 16 + hh) * 64 + dd) * 1024 + ss) = pk;
      } else {
#pragma unroll
        for (int r = 0; r < 4; ++r)
          Cb[(size_t)(gm + i * 16 + lhi * 4 + r) * N + gcol] = (f16_t)v4[r];
      }
    }
  }
}

// ---------------------------------------------------------------------------
// Flash attention, MFMA. Geometry: one block = (b, h, 256 q-rows),
// 8 waves (512 thr); wave w owns q-rows w*32..+31 -- per-wave inner code is
// IDENTICAL to the proven 91-us version. Q staged through SP. Gains: K/V
// staging traffic per CU halved, waves/CU 12 -> 16 at 3 blocks/CU (50 KB
// LDS). K/V tiles of 64 keys; V pre-transposed vt[b][h][d][s]. Scale 0.125.
// ---------------------------------------------------------------------------
__global__ __launch_bounds__(512, 6) void attn_mfma(const f16_t* __restrict__ q,
                                                    const f16_t* __restrict__ k,
                                                    const f16_t* __restrict__ vt,
                                                    f16_t* __restrict__ wv) {
  const int S = 1024, D = 1024;
  __shared__ __align__(16) f16_t SP[256 * 64];   // Q staging, then P (32 KB)
  __shared__ __align__(16) f16_t Ks[64 * 64];
  __shared__ __align__(16) f16_t Vts[64 * 64];
  __shared__ float rsb[256];
  __shared__ float lib[256];
  const int tid = threadIdx.x, lane = tid & 63, w = tid >> 6;  // w in 0..7
  const int l15 = lane & 15, lhi = lane >> 4;
  const int q0 = blockIdx.x * 256;
  const int h = blockIdx.y, b = blockIdx.z;
  const f16_t* qg = q + ((size_t)b * S + q0) * D + h * 64;
  const f16_t* kg = k + (size_t)b * S * D + h * 64;
  const f16_t* vg = vt + ((size_t)b * 16 + h) * 64 * (size_t)S;

  // stage Q tile (256 rows) into SP, swizzled rows of 128 B
#pragma unroll
  for (int c = 0; c < 4; ++c) {
    int idx = c * 512 + tid;
    int r = idx >> 3, kc = idx & 7;
    f16x8 xx = *(const f16x8*)(qg + (size_t)r * D + kc * 8);
    *(f16x8*)((char*)SP + r * 128 + ((kc * 16) ^ ((r & 7) << 4))) = xx;
  }
  __syncthreads();
  // hoist Q fragments (wave w owns rows w*32..+31)
  f16x8 qf[2][2];
#pragma unroll
  for (int i = 0; i < 2; ++i) {
    int row = w * 32 + i * 16 + l15;
#pragma unroll
    for (int kk = 0; kk < 2; ++kk)
      qf[i][kk] = *(const f16x8*)((char*)SP + row * 128 +
                                  ((kk * 64 + lhi * 16) ^ ((row & 7) << 4)));
  }

  f32x4 oacc[2][4];
#pragma unroll
  for (int i = 0; i < 2; ++i)
#pragma unroll
    for (int j = 0; j < 4; ++j) oacc[i][j] = (f32x4){0.f, 0.f, 0.f, 0.f};
  float m_run = -1e30f, l_run = 0.f;
  const int myrow = w * 32 + (lane >> 1);
  const int half = lane & 1;

  for (int kv = 0; kv < 16; ++kv) {
    __syncthreads();  // K/V/SP safe to overwrite (all readers past)
    {
      int r = tid >> 3, kc = tid & 7;  // 512 threads = 64 rows x 8 slots
      f16x8 xk = *(const f16x8*)(kg + (size_t)(kv * 64 + r) * D + kc * 8);
      *(f16x8*)((char*)Ks + r * 128 + ((kc * 16) ^ ((r & 7) << 4))) = xk;
      f16x8 xv = *(const f16x8*)(vg + (size_t)r * S + kv * 64 + kc * 8);
      *(f16x8*)((char*)Vts + r * 128 + ((kc * 16) ^ ((r & 7) << 4))) = xv;
    }
    __syncthreads();
    // QK^T
    f32x4 sacc[2][4];
#pragma unroll
    for (int i = 0; i < 2; ++i)
#pragma unroll
      for (int j = 0; j < 4; ++j) sacc[i][j] = (f32x4){0.f, 0.f, 0.f, 0.f};
#pragma unroll
    for (int kk = 0; kk < 2; ++kk) {
      f16x8 kf[4];
#pragma unroll
      for (int j = 0; j < 4; ++j) {
        int row = j * 16 + l15;
        kf[j] = *(const f16x8*)((char*)Ks + row * 128 +
                                ((kk * 64 + lhi * 16) ^ ((row & 7) << 4)));
      }
#pragma unroll
      for (int i = 0; i < 2; ++i)
#pragma unroll
        for (int j = 0; j < 4; ++j) sacc[i][j] = MFMA16(qf[i][kk], kf[j], sacc[i][j]);
    }
    // scatter scaled scores to SP (f16, swizzled)
#pragma unroll
    for (int i = 0; i < 2; ++i)
#pragma unroll
      for (int j = 0; j < 4; ++j)
#pragma unroll
        for (int r = 0; r < 4; ++r) {
          int srow = w * 32 + i * 16 + lhi * 4 + r;
          int scol = j * 16 + l15;
          *(f16_t*)((char*)SP + srow * 128 + ((scol * 2) ^ ((srow & 7) << 4))) =
              (f16_t)(sacc[i][j][r] * 0.125f);
        }
    __syncthreads();
    // online softmax: 2 lanes per row, 32 keys each; exp in place -> P
    f16x8 ch[4];
#pragma unroll
    for (int c = 0; c < 4; ++c)
      ch[c] = *(const f16x8*)((char*)SP + myrow * 128 +
                              ((half * 64 + c * 16) ^ ((myrow & 7) << 4)));
    float mt = -1e30f;
#pragma unroll
    for (int c = 0; c < 4; ++c)
#pragma unroll
      for (int e = 0; e < 8; ++e) mt = fmaxf(mt, (float)ch[c][e]);
    mt = fmaxf(mt, __shfl_xor(mt, 1));
    float mnew = fmaxf(m_run, mt);
    float resc = __expf(m_run - mnew);
    float lsum = 0.f;
#pragma unroll
    for (int c = 0; c < 4; ++c) {
      f16x8 p8;
#pragma unroll
      for (int e = 0; e < 8; ++e) {
        float p = __expf((float)ch[c][e] - mnew);
        lsum += p;
        p8[e] = (f16_t)p;
      }
      *(f16x8*)((char*)SP + myrow * 128 + ((half * 64 + c * 16) ^ ((myrow & 7) << 4))) = p8;
    }
    lsum += __shfl_xor(lsum, 1);
    l_run = l_run * resc + lsum;
    m_run = mnew;
    if (half == 0) rsb[myrow] = resc;
    __syncthreads();
    // rescale O accumulator, then PV
#pragma unroll
    for (int i = 0; i < 2; ++i) {
      float f0 = rsb[w * 32 + i * 16 + lhi * 4 + 0];
      float f1 = rsb[w * 32 + i * 16 + lhi * 4 + 1];
      float f2 = rsb[w * 32 + i * 16 + lhi * 4 + 2];
      float f3 = rsb[w * 32 + i * 16 + lhi * 4 + 3];
#pragma unroll
      for (int j = 0; j < 4; ++j) {
        oacc[i][j][0] *= f0;
        oacc[i][j][1] *= f1;
        oacc[i][j][2] *= f2;
        oacc[i][j][3] *= f3;
      }
    }
#pragma unroll
    for (int kk = 0; kk < 2; ++kk) {
      f16x8 pa[2], vb[4];
#pragma unroll
      for (int i = 0; i < 2; ++i) {
        int row = w * 32 + i * 16 + l15;
        pa[i] = *(const f16x8*)((char*)SP + row * 128 +
                                ((kk * 64 + lhi * 16) ^ ((row & 7) << 4)));
      }
#pragma unroll
      for (int j = 0; j < 4; ++j) {
        int row = j * 16 + l15;
        vb[j] = *(const f16x8*)((char*)Vts + row * 128 +
                                ((kk * 64 + lhi * 16) ^ ((row & 7) << 4)));
      }
#pragma unroll
      for (int i = 0; i < 2; ++i)
#pragma unroll
        for (int j = 0; j < 4; ++j) oacc[i][j] = MFMA16(pa[i], vb[j], oacc[i][j]);
    }
  }
  if (half == 0) lib[myrow] = 1.f / l_run;
  __syncthreads();
#pragma unroll
  for (int i = 0; i < 2; ++i)
#pragma unroll
    for (int r = 0; r < 4; ++r) {
      int row = w * 32 + i * 16 + lhi * 4 + r;
      float li = lib[row];
      size_t base = ((size_t)b * S + q0 + row) * D + h * 64;
#pragma unroll
      for (int j = 0; j < 4; ++j)
        wv[base + j * 16 + l15] = (f16_t)(oacc[i][j][r] * li);
    }
}

// ---------------------------------------------------------------------------
extern "C" void kernel_launch(void* const* d_in, const int* in_sizes, int n_in,
                              void* d_out, int out_size, void* d_ws, size_t ws_size,
                              hipStream_t stream) {
  const int B = 8, S = 1024, D = 1024, F = 4096;
  const int M = B * S;  // 8192

  const float* x = (const float*)d_in[0];
  const float* Wq = (const float*)d_in[1];
  const float* bq = (const float*)d_in[2];
  const float* Wk = (const float*)d_in[3];
  const float* Wv = (const float*)d_in[4];
  const float* bv = (const float*)d_in[5];
  const float* Wo = (const float*)d_in[6];
  const float* bo = (const float*)d_in[7];
  const float* la_k = (const float*)d_in[8];
  const float* lb_k = (const float*)d_in[9];
  const float* la_v = (const float*)d_in[10];
  const float* lb_v = (const float*)d_in[11];
  const float* la_o = (const float*)d_in[12];
  const float* lb_o = (const float*)d_in[13];
  const float* g_attn = (const float*)d_in[14];
  const float* b_attn = (const float*)d_in[15];
  const float* W1 = (const float*)d_in[16];
  const float* b1 = (const float*)d_in[17];
  const float* W2 = (const float*)d_in[18];
  const float* b2 = (const float*)d_in[19];
  const float* g_mlp = (const float*)d_in[20];
  const float* b_mlp = (const float*)d_in[21];

  // ---- workspace layout ----
  // [16B pad][t_k][t_v][t_o fp32, ~384KB] [P0][P1][P2][P3] (16 MiB each, f16)
  // [Wqkvf 3D*D][Wof D*D][W1f F*D][W2f D*F] f16 weights (24 MiB total).
  float* t_k = (float*)((char*)d_ws + 16);
  float* t_v = t_k + (size_t)M * 4;
  float* t_o = t_v + (size_t)M * 4;
  const size_t MD = (size_t)M * D;
  f16_t* P0 = (f16_t*)((char*)d_ws + 409600);
  f16_t* P1 = P0 + MD;
  f16_t* P2 = P0 + 2 * MD;
  f16_t* P3 = P0 + 3 * MD;
  f16_t* Wqkvf = P0 + 4 * MD;                  // [3072,1024] f16
  f16_t* Wof = Wqkvf + 3 * (size_t)D * D;
  f16_t* W1f = Wof + (size_t)D * D;
  f16_t* W2f = W1f + (size_t)F * D;
  float* outf = (float*)d_out;
  const size_t need = 409600 + 4 * MD * sizeof(f16_t) +
                      (4 * (size_t)D * D + 2 * (size_t)F * D) * sizeof(f16_t);
  const bool f16w = ws_size >= need;

  if (f16w)
    convert_w<<<6144, 256, 0, stream>>>(
        Wq, Wk, Wv, Wo, W1, W2, Wqkvf, Wqkvf + (size_t)D * D,
        Wqkvf + 2 * (size_t)D * D, Wof, W1f, W2f);

  // 1+2. h = LN(x) -> P0, fused with LoRA t_k/t_v
  ln_lora_f32<<<M, 256, 0, stream>>>(x, g_attn, b_attn, la_k, la_v, P0, t_k, t_v);
  // 3. fused QKV projection: q -> P1, k -> P2, v -> P3 ([B,H,64,S] transposed)
  if (f16w) {
    gemm_qkv_pipe<<<dim3(12, 64), 512, 0, stream>>>(
        P0, Wqkvf, bq, bv, t_k, lb_k, t_v, lb_v, P1, P2, P3, D);
  } else {
    gemm_mfma<<<dim3(8, 64), 256, 0, stream>>>(
        P0, Wq, bq, nullptr, nullptr, nullptr, nullptr, P1, nullptr, nullptr,
        M, D, D, D, 0);
    gemm_mfma<<<dim3(8, 64), 256, 0, stream>>>(
        P0, Wk, nullptr, t_k, lb_k, nullptr, nullptr, P2, nullptr, nullptr,
        M, D, D, D, 0);
    gemm_mfma<<<dim3(8, 64), 256, 0, stream>>>(
        P0, Wv, bv, t_v, lb_v, nullptr, nullptr, nullptr, nullptr, P3,
        M, D, D, D, 0);
  }
  // 4. attention -> wv (f16) -> P0 (h dead); 256-q-row blocks
  attn_mfma<<<dim3(4, 16, 8), 512, 0, stream>>>(P1, P2, P3, P0);
  // 5. LoRA t for o (input wv)
  lora_t_kernel<<<M / 4, 256, 0, stream>>>(P0, la_o, t_o, D);
  // 6. x1 = x + wv @ Wo^T + bo + lora_o -> P3 (f16; q/k/Vt dead)
  if (f16w)
    gemm_pipe<<<dim3(4, 64), 512, 0, stream>>>(
        P0, Wof, bo, t_o, lb_o, x, nullptr, P3, nullptr, M, D, D, D, 0);
  else
    gemm_mfma<<<dim3(8, 64), 256, 0, stream>>>(
        P0, Wo, bo, t_o, lb_o, x, nullptr, P3, nullptr, nullptr, M, D, D, D, 0);
  // 7. h2 = LN(x1) -> P0 (wv dead)
  ln_f16<<<M, 256, 0, stream>>>(P3, g_mlp, b_mlp, P0);
  // 8/9. MLP in two N=2048 halves: u -> P1∪P2, out accumulates on d_out (f32)
  if (f16w) {
    gemm_pipe<<<dim3(8, 64), 512, 0, stream>>>(
        P0, W1f, b1, nullptr, nullptr, nullptr, nullptr, P1, nullptr,
        M, 2048, D, D, 1);
    gemm_pipe<<<dim3(4, 64), 512, 0, stream>>>(
        P1, W2f, b2, nullptr, nullptr, nullptr, P3, nullptr, outf,
        M, D, 2048, F, 0);
    gemm_pipe<<<dim3(8, 64), 512, 0, stream>>>(
        P0, W1f + (size_t)2048 * D, b1 + 2048, nullptr, nullptr, nullptr, nullptr,
        P1, nullptr, M, 2048, D, D, 1);
    gemm_pipe<<<dim3(4, 64), 512, 0, stream>>>(
        P1, W2f + 2048, nullptr, nullptr, nullptr, outf, nullptr, nullptr, outf,
        M, D, 2048, F, 0);
  } else {
    gemm_mfma<<<dim3(16, 64), 256, 0, stream>>>(
        P0, W1, b1, nullptr, nullptr, nullptr, nullptr, P1, nullptr, nullptr,
        M, 2048, D, D, 1);
    gemm_mfma<<<dim3(8, 64), 256, 0, stream>>>(
        P1, W2, b2, nullptr, nullptr, nullptr, P3, nullptr, outf, nullptr,
        M, D, 2048, F, 0);
    gemm_mfma<<<dim3(16, 64), 256, 0, stream>>>(
        P0, W1 + (size_t)2048 * D, b1 + 2048, nullptr, nullptr, nullptr, nullptr,
        P1, nullptr, nullptr, M, 2048, D, D, 1);
    gemm_mfma<<<dim3(8, 64), 256, 0, stream>>>(
        P1, W2 + 2048, nullptr, nullptr, nullptr, outf, nullptr, nullptr, outf,
        nullptr, M, D, 2048, F, 0);
  }
}

// Round 14
// 660.215 us; speedup vs baseline: 1.3013x; 1.3013x over previous
//
#include <hip/hip_runtime.h>
#include <math.h>

typedef _Float16 f16_t;
typedef f16_t f16x8 __attribute__((ext_vector_type(8)));
typedef f16_t f16x4 __attribute__((ext_vector_type(4)));
typedef float f32x4 __attribute__((ext_vector_type(4)));
typedef float fv4 __attribute__((ext_vector_type(4)));

#define MFMA16(a, b, c) __builtin_amdgcn_mfma_f32_16x16x32_f16(a, b, c, 0, 0, 0)

__device__ __forceinline__ void gload16(const void* g, void* l) {
  __builtin_amdgcn_global_load_lds((const __attribute__((address_space(1))) void*)g,
                                   (__attribute__((address_space(3))) void*)l, 16, 0, 0);
}

// ---------------------------------------------------------------------------
// Fused LayerNorm (fp32 -> f16) + LoRA-kv first stage.
// One 256-thread block per row: y = LN(x), t_k[row] = y @ la_k^T,
// t_v[row] = y @ la_v^T (computed from the f32 y -- more accurate than f16).
// ---------------------------------------------------------------------------
__global__ __launch_bounds__(256) void ln_lora_f32(
    const float* __restrict__ x, const float* __restrict__ g,
    const float* __restrict__ b, const float* __restrict__ la_k,
    const float* __restrict__ la_v, f16_t* __restrict__ y,
    float* __restrict__ t_k, float* __restrict__ t_v) {
  const int D = 1024;
  int row = blockIdx.x;
  int t = threadIdx.x;
  const float* xr = x + (size_t)row * D + t * 4;
  float x0 = xr[0], x1 = xr[1], x2 = xr[2], x3 = xr[3];
  float sum = x0 + x1 + x2 + x3;
  float sq = x0 * x0 + x1 * x1 + x2 * x2 + x3 * x3;
  for (int d = 32; d; d >>= 1) {
    sum += __shfl_down(sum, d);
    sq += __shfl_down(sq, d);
  }
  __shared__ float ssum[4], ssq[4];
  __shared__ float red[4][8];
  int w = t >> 6, lane = t & 63;
  if (lane == 0) { ssum[w] = sum; ssq[w] = sq; }
  __syncthreads();
  float ts = ssum[0] + ssum[1] + ssum[2] + ssum[3];
  float tq = ssq[0] + ssq[1] + ssq[2] + ssq[3];
  float mean = ts * (1.0f / 1024.0f);
  float var = tq * (1.0f / 1024.0f) - mean * mean;
  float rstd = rsqrtf(var + 1e-5f);
  const float* gr = g + t * 4;
  const float* br = b + t * 4;
  float y0 = (x0 - mean) * rstd * gr[0] + br[0];
  float y1 = (x1 - mean) * rstd * gr[1] + br[1];
  float y2 = (x2 - mean) * rstd * gr[2] + br[2];
  float y3 = (x3 - mean) * rstd * gr[3] + br[3];
  f16_t* yr = y + (size_t)row * D + t * 4;
  yr[0] = (f16_t)y0; yr[1] = (f16_t)y1; yr[2] = (f16_t)y2; yr[3] = (f16_t)y3;
  // LoRA-kv dots: a[0..3] = k-rows, a[4..7] = v-rows
  float a[8];
#pragma unroll
  for (int r = 0; r < 4; ++r) {
    const float* kr = la_k + (size_t)r * D + t * 4;
    const float* vr = la_v + (size_t)r * D + t * 4;
    a[r] = y0 * kr[0] + y1 * kr[1] + y2 * kr[2] + y3 * kr[3];
    a[4 + r] = y0 * vr[0] + y1 * vr[1] + y2 * vr[2] + y3 * vr[3];
  }
#pragma unroll
  for (int i = 0; i < 8; ++i)
    for (int d = 32; d; d >>= 1) a[i] += __shfl_down(a[i], d);
  if (lane == 0) {
#pragma unroll
    for (int i = 0; i < 8; ++i) red[w][i] = a[i];
  }
  __syncthreads();
  if (t < 8) {
    float s = red[0][t] + red[1][t] + red[2][t] + red[3][t];
    if (t < 4) t_k[(size_t)row * 4 + t] = s;
    else t_v[(size_t)row * 4 + (t - 4)] = s;
  }
}

// LayerNorm, f16 input -> f16 output.
__global__ __launch_bounds__(256) void ln_f16(const f16_t* __restrict__ x,
                                              const float* __restrict__ g,
                                              const float* __restrict__ b,
                                              f16_t* __restrict__ y) {
  const int D = 1024;
  int row = blockIdx.x;
  int t = threadIdx.x;
  const f16_t* xr = x + (size_t)row * D + t * 4;
  float x0 = (float)xr[0], x1 = (float)xr[1], x2 = (float)xr[2], x3 = (float)xr[3];
  float sum = x0 + x1 + x2 + x3;
  float sq = x0 * x0 + x1 * x1 + x2 * x2 + x3 * x3;
  for (int d = 32; d; d >>= 1) {
    sum += __shfl_down(sum, d);
    sq += __shfl_down(sq, d);
  }
  __shared__ float ssum[4], ssq[4];
  int w = t >> 6, lane = t & 63;
  if (lane == 0) { ssum[w] = sum; ssq[w] = sq; }
  __syncthreads();
  float ts = ssum[0] + ssum[1] + ssum[2] + ssum[3];
  float tq = ssq[0] + ssq[1] + ssq[2] + ssq[3];
  float mean = ts * (1.0f / 1024.0f);
  float var = tq * (1.0f / 1024.0f) - mean * mean;
  float rstd = rsqrtf(var + 1e-5f);
  f16_t* yr = y + (size_t)row * D + t * 4;
  const float* gr = g + t * 4;
  const float* br = b + t * 4;
  yr[0] = (f16_t)((x0 - mean) * rstd * gr[0] + br[0]);
  yr[1] = (f16_t)((x1 - mean) * rstd * gr[1] + br[1]);
  yr[2] = (f16_t)((x2 - mean) * rstd * gr[2] + br[2]);
  yr[3] = (f16_t)((x3 - mean) * rstd * gr[3] + br[3]);
}

// ---------------------------------------------------------------------------
// Weight convert fp32 -> f16, one fused launch for all 6 matrices.
// (q/k/v write into one contiguous [3072,1024] blob via the o* pointers.)
// ---------------------------------------------------------------------------
__global__ __launch_bounds__(256) void convert_w(
    const float* __restrict__ wq, const float* __restrict__ wk,
    const float* __restrict__ wv, const float* __restrict__ wo,
    const float* __restrict__ w1, const float* __restrict__ w2,
    f16_t* __restrict__ oq, f16_t* __restrict__ ok, f16_t* __restrict__ ov,
    f16_t* __restrict__ oo, f16_t* __restrict__ o1, f16_t* __restrict__ o2) {
  int bid = blockIdx.x;
  const float* src;
  f16_t* dst;
  int bi;
  if (bid < 2048) {
    int seg = bid >> 9;
    bi = bid & 511;
    src = seg == 0 ? wq : seg == 1 ? wk : seg == 2 ? wv : wo;
    dst = seg == 0 ? oq : seg == 1 ? ok : seg == 2 ? ov : oo;
  } else if (bid < 4096) {
    bi = bid - 2048; src = w1; dst = o1;
  } else {
    bi = bid - 4096; src = w2; dst = o2;
  }
  size_t idx = (size_t)bi * 2048 + (size_t)threadIdx.x * 8;
  fv4 a = *(const fv4*)(src + idx);
  fv4 b = *(const fv4*)(src + idx + 4);
  f16x8 h;
#pragma unroll
  for (int j = 0; j < 4; ++j) { h[j] = (f16_t)a[j]; h[4 + j] = (f16_t)b[j]; }
  *(f16x8*)(dst + idx) = h;
}

// LoRA first stage, single matrix (o-projection).
__global__ __launch_bounds__(256) void lora_t_kernel(const f16_t* __restrict__ h,
                                                     const float* __restrict__ la,
                                                     float* __restrict__ t, int K) {
  int lane = threadIdx.x & 63;
  int w = threadIdx.x >> 6;
  int row = blockIdx.x * 4 + w;
  const f16_t* hrow = h + (size_t)row * K;
  float acc[4] = {0.f, 0.f, 0.f, 0.f};
  for (int it = 0; it < K / 512; ++it) {
    int base = it * 512 + lane * 8;
    f16x8 hx = *(const f16x8*)(hrow + base);
#pragma unroll
    for (int r = 0; r < 4; ++r) {
      const float* ar = la + (size_t)r * K + base;
#pragma unroll
      for (int j = 0; j < 8; ++j) acc[r] += (float)hx[j] * ar[j];
    }
  }
#pragma unroll
  for (int r = 0; r < 4; ++r) {
    for (int d = 32; d; d >>= 1) acc[r] += __shfl_down(acc[r], d);
  }
  if (lane == 0) {
#pragma unroll
    for (int r = 0; r < 4; ++r) t[(size_t)row * 4 + r] = acc[r];
  }
}

// ===========================================================================
// PIPELINED MFMA f16 GEMM core (unchanged from R8, +5% proven): 128x256 tile,
// BK=64, 512 threads, 3-deep LDS (144 KB), counted-vmcnt pipeline.
// ===========================================================================
#define GEMM_PIPE_BODY                                                        \
  f32x4 acc[4][4];                                                            \
  _Pragma("unroll") for (int i = 0; i < 4; ++i)                               \
      _Pragma("unroll") for (int j = 0; j < 4; ++j)                           \
          acc[i][j] = (f32x4){0.f, 0.f, 0.f, 0.f};                            \
  const int nsteps = K >> 6;                                                  \
  stageA(0, 0); stageB(0, 0);                                                 \
  stageA(1, 1); stageB(1, 1);                                                 \
  stageA(2, 2); stageB(2, 2);                                                 \
  int b3 = 0;                                                                 \
  for (int kt = 0; kt < nsteps; ++kt) {                                       \
    if (kt + 2 < nsteps)                                                      \
      asm volatile("s_waitcnt vmcnt(12)" ::: "memory");                       \
    else if (kt + 1 < nsteps)                                                 \
      asm volatile("s_waitcnt vmcnt(6)" ::: "memory");                        \
    else                                                                      \
      asm volatile("s_waitcnt vmcnt(0)" ::: "memory");                        \
    __builtin_amdgcn_sched_barrier(0);                                        \
    __builtin_amdgcn_s_barrier();                                             \
    f16x8 af[4][2], bf[4][2];                                                 \
    _Pragma("unroll") for (int kk = 0; kk < 2; ++kk) {                        \
      _Pragma("unroll") for (int i = 0; i < 4; ++i) {                         \
        int row = wm * 64 + i * 16 + l15;                                     \
        af[i][kk] = *(const f16x8*)((const char*)Abuf[b3] + row * 128 +       \
                                    ((kk * 64 + lhi * 16) ^ ((row & 7) << 4)));\
      }                                                                       \
      _Pragma("unroll") for (int j = 0; j < 4; ++j) {                         \
        int row = wn * 64 + j * 16 + l15;                                     \
        bf[j][kk] = *(const f16x8*)((const char*)Bbuf[b3] + row * 128 +       \
                                    ((kk * 64 + lhi * 16) ^ ((row & 7) << 4)));\
      }                                                                       \
    }                                                                         \
    asm volatile("s_waitcnt lgkmcnt(0)" ::: "memory");                        \
    __builtin_amdgcn_sched_barrier(0);                                        \
    __builtin_amdgcn_s_barrier();                                             \
    if (kt + 3 < nsteps) { stageA(kt + 3, b3); stageB(kt + 3, b3); }          \
    __builtin_amdgcn_sched_barrier(0);                                        \
    __builtin_amdgcn_s_setprio(1);                                            \
    _Pragma("unroll") for (int kk = 0; kk < 2; ++kk)                          \
        _Pragma("unroll") for (int i = 0; i < 4; ++i)                         \
            _Pragma("unroll") for (int j = 0; j < 4; ++j)                     \
                acc[i][j] = MFMA16(af[i][kk], bf[j][kk], acc[i][j]);          \
    __builtin_amdgcn_s_setprio(0);                                            \
    b3 = (b3 == 2) ? 0 : b3 + 1;                                              \
  }

// ---------------------------------------------------------------------------
// Pipelined GEMM with generic epilogue.
// ---------------------------------------------------------------------------
__global__ __launch_bounds__(512, 2) void gemm_pipe(
    const f16_t* __restrict__ A, const f16_t* __restrict__ B,
    const float* __restrict__ bias, const float* __restrict__ loraT,
    const float* __restrict__ loraB, const float* residf,
    const f16_t* __restrict__ residb, f16_t* Cb, float* Cf,
    int M, int N, int K, int ldb, int dogelu) {
  __shared__ __align__(16) f16_t Abuf[3][8192];
  __shared__ __align__(16) f16_t Bbuf[3][16384];
  const int tid = threadIdx.x;
  const int lane = tid & 63, wid = tid >> 6;
  const int wm = wid >> 2, wn = wid & 3;
  const int l15 = lane & 15, lhi = lane >> 4;
  int nwg = gridDim.x * gridDim.y;
  int bid = blockIdx.y * gridDim.x + blockIdx.x;
  int swz = (bid & 7) * (nwg >> 3) + (bid >> 3);
  const int m0 = (swz / gridDim.x) * 128, n0 = (swz % gridDim.x) * 256;
  const int arow = tid >> 3;
  const int aslot = tid & 7;

  auto stageA = [&](int step, int buf) {
#pragma unroll
    for (int c = 0; c < 2; ++c) {
      int r = c * 64 + arow;
      int cm = aslot ^ (r & 7);
      gload16(A + (size_t)(m0 + r) * K + (size_t)step * 64 + cm * 8,
              (char*)Abuf[buf] + c * 8192 + wid * 1024);
    }
  };
  auto stageB = [&](int step, int buf) {
#pragma unroll
    for (int c = 0; c < 4; ++c) {
      int r = c * 64 + arow;
      int cm = aslot ^ (r & 7);
      gload16(B + (size_t)(n0 + r) * ldb + (size_t)step * 64 + cm * 8,
              (char*)Bbuf[buf] + c * 8192 + wid * 1024);
    }
  };

  GEMM_PIPE_BODY

  const int gm = m0 + wm * 64, gn = n0 + wn * 64;
#pragma unroll
  for (int j = 0; j < 4; ++j) {
    int gcol = gn + j * 16 + l15;
    float bj = bias ? bias[gcol] : 0.f;
    float lb0 = 0.f, lb1 = 0.f, lb2 = 0.f, lb3 = 0.f;
    if (loraB) {
      const float* p = loraB + (size_t)gcol * 4;
      lb0 = p[0]; lb1 = p[1]; lb2 = p[2]; lb3 = p[3];
    }
#pragma unroll
    for (int i = 0; i < 4; ++i) {
      float v4[4];
#pragma unroll
      for (int r = 0; r < 4; ++r) {
        int grow = gm + i * 16 + lhi * 4 + r;
        float val = acc[i][j][r] + bj;
        if (loraT) {
          const float* tp = loraT + (size_t)grow * 4;
          val += 0.25f * (tp[0] * lb0 + tp[1] * lb1 + tp[2] * lb2 + tp[3] * lb3);
        }
        if (dogelu) val = 0.5f * val * (1.0f + erff(val * 0.70710678118654752f));
        if (residf) val += residf[(size_t)grow * N + gcol];
        if (residb) val += (float)residb[(size_t)grow * N + gcol];
        v4[r] = val;
      }
      if (Cf) {
#pragma unroll
        for (int r = 0; r < 4; ++r)
          Cf[(size_t)(gm + i * 16 + lhi * 4 + r) * N + gcol] = v4[r];
      } else {
#pragma unroll
        for (int r = 0; r < 4; ++r)
          Cb[(size_t)(gm + i * 16 + lhi * 4 + r) * N + gcol] = (f16_t)v4[r];
      }
    }
  }
}

// ---------------------------------------------------------------------------
// Pipelined fused QKV GEMM (unchanged from R8).
// ---------------------------------------------------------------------------
__global__ __launch_bounds__(512, 2) void gemm_qkv_pipe(
    const f16_t* __restrict__ A, const f16_t* __restrict__ W,
    const float* __restrict__ bq, const float* __restrict__ bv,
    const float* __restrict__ t_k, const float* __restrict__ lb_k,
    const float* __restrict__ t_v, const float* __restrict__ lb_v,
    f16_t* __restrict__ Pq, f16_t* __restrict__ Pk, f16_t* __restrict__ Pvt,
    int K) {
  const int D = 1024;
  __shared__ __align__(16) f16_t Abuf[3][8192];
  __shared__ __align__(16) f16_t Bbuf[3][16384];
  const int tid = threadIdx.x;
  const int lane = tid & 63, wid = tid >> 6;
  const int wm = wid >> 2, wn = wid & 3;
  const int l15 = lane & 15, lhi = lane >> 4;
  int nwg = gridDim.x * gridDim.y;
  int bid = blockIdx.y * gridDim.x + blockIdx.x;
  int swz = (bid & 7) * (nwg >> 3) + (bid >> 3);
  const int m0 = (swz / gridDim.x) * 128, n0 = (swz % gridDim.x) * 256;
  const int seg = n0 >> 10;
  const int arow = tid >> 3;
  const int aslot = tid & 7;

  auto stageA = [&](int step, int buf) {
#pragma unroll
    for (int c = 0; c < 2; ++c) {
      int r = c * 64 + arow;
      int cm = aslot ^ (r & 7);
      gload16(A + (size_t)(m0 + r) * K + (size_t)step * 64 + cm * 8,
              (char*)Abuf[buf] + c * 8192 + wid * 1024);
    }
  };
  auto stageB = [&](int step, int buf) {
#pragma unroll
    for (int c = 0; c < 4; ++c) {
      int r = c * 64 + arow;
      int cm = aslot ^ (r & 7);
      gload16(W + (size_t)(n0 + r) * K + (size_t)step * 64 + cm * 8,
              (char*)Bbuf[buf] + c * 8192 + wid * 1024);
    }
  };

  GEMM_PIPE_BODY

  const int gm = m0 + wm * 64, gn = n0 + wn * 64;
  const float* tB = (seg == 1) ? t_k : t_v;
#pragma unroll
  for (int j = 0; j < 4; ++j) {
    int gcol = gn + j * 16 + l15;
    int c = gcol & 1023;
    float bj = (seg == 0) ? bq[c] : (seg == 2 ? bv[c] : 0.f);
    float lb0 = 0.f, lb1 = 0.f, lb2 = 0.f, lb3 = 0.f;
    if (seg) {
      const float* p = (seg == 1 ? lb_k : lb_v) + (size_t)c * 4;
      lb0 = p[0]; lb1 = p[1]; lb2 = p[2]; lb3 = p[3];
    }
#pragma unroll
    for (int i = 0; i < 4; ++i) {
      float v4[4];
#pragma unroll
      for (int r = 0; r < 4; ++r) {
        int grow = gm + i * 16 + lhi * 4 + r;
        float val = acc[i][j][r] + bj;
        if (seg) {
          const float* tp = tB + (size_t)grow * 4;
          val += 0.25f * (tp[0] * lb0 + tp[1] * lb1 + tp[2] * lb2 + tp[3] * lb3);
        }
        v4[r] = val;
      }
      if (seg < 2) {
        f16_t* dst = (seg == 0) ? Pq : Pk;
#pragma unroll
        for (int r = 0; r < 4; ++r)
          dst[(size_t)(gm + i * 16 + lhi * 4 + r) * D + c] = (f16_t)v4[r];
      } else {
        int grow0 = gm + i * 16 + lhi * 4;
        int bb = grow0 >> 10, ss = grow0 & 1023;
        int hh = c >> 6, dd = c & 63;
        f16x4 pk;
#pragma unroll
        for (int r = 0; r < 4; ++r) pk[r] = (f16_t)v4[r];
        *(f16x4*)(Pvt + (((size_t)bb * 16 + hh) * 64 + dd) * 1024 + ss) = pk;
      }
    }
  }
}

// ---------------------------------------------------------------------------
// Fallback GEMM (B fp32, reg-staged + converted); used only when ws_size
// can't hold f16 weights. Full epilogue incl. transposed-V output.
// ---------------------------------------------------------------------------
__global__ __launch_bounds__(256, 2) void gemm_mfma(
    const f16_t* __restrict__ A, const float* __restrict__ B,
    const float* __restrict__ bias, const float* __restrict__ loraT,
    const float* __restrict__ loraB, const float* residf,
    const f16_t* __restrict__ residb, f16_t* Cb, float* Cf, f16_t* Cvt,
    int M, int N, int K, int ldb, int dogelu) {
  __shared__ __align__(16) f16_t smem[2][16384];
  const int tid = threadIdx.x;
  const int lane = tid & 63, wid = tid >> 6;
  const int wm = wid >> 1, wn = wid & 1;
  const int l15 = lane & 15, lhi = lane >> 4;
  const int m0 = blockIdx.y * 128, n0 = blockIdx.x * 128;
  const int arow = tid >> 3;
  const int aslot = tid & 7;

  f32x4 acc[4][4];
#pragma unroll
  for (int i = 0; i < 4; ++i)
#pragma unroll
    for (int j = 0; j < 4; ++j) acc[i][j] = (f32x4){0.f, 0.f, 0.f, 0.f};

  fv4 breg[4][2];

  auto stageA = [&](int step, int buf) {
#pragma unroll
    for (int c = 0; c < 4; ++c) {
      int r = c * 32 + arow;
      int cm = aslot ^ (r & 7);
      gload16(A + (size_t)(m0 + r) * K + (size_t)step * 64 + cm * 8,
              (char*)&smem[buf][0] + c * 4096 + wid * 1024);
    }
  };
  auto loadB = [&](int step) {
#pragma unroll
    for (int c = 0; c < 4; ++c) {
      int r = c * 32 + arow;
      const float* gp = B + (size_t)(n0 + r) * ldb + (size_t)step * 64 + aslot * 8;
      breg[c][0] = *(const fv4*)gp;
      breg[c][1] = *(const fv4*)(gp + 4);
    }
  };
  auto writeB = [&](int buf) {
#pragma unroll
    for (int c = 0; c < 4; ++c) {
      int r = c * 32 + arow;
      f16x8 hh;
#pragma unroll
      for (int j = 0; j < 4; ++j) hh[j] = (f16_t)breg[c][0][j];
#pragma unroll
      for (int j = 0; j < 4; ++j) hh[4 + j] = (f16_t)breg[c][1][j];
      int boff = r * 128 + ((aslot * 16) ^ ((r & 7) << 4));
      *(f16x8*)((char*)&smem[buf][8192] + boff) = hh;
    }
  };

  const int nsteps = K >> 6;
  stageA(0, 0);
  loadB(0);
  writeB(0);
  __syncthreads();
  for (int t = 0; t < nsteps; ++t) {
    int cur = t & 1, nxt = cur ^ 1;
    if (t + 1 < nsteps) { stageA(t + 1, nxt); loadB(t + 1); }
    const char* As = (const char*)&smem[cur][0];
    const char* Bs = (const char*)&smem[cur][8192];
#pragma unroll
    for (int kk = 0; kk < 2; ++kk) {
      f16x8 af[4], bf[4];
#pragma unroll
      for (int i = 0; i < 4; ++i) {
        int row = wm * 64 + i * 16 + l15;
        af[i] = *(const f16x8*)(As + row * 128 + ((kk * 64 + lhi * 16) ^ ((row & 7) << 4)));
      }
#pragma unroll
      for (int j = 0; j < 4; ++j) {
        int row = wn * 64 + j * 16 + l15;
        bf[j] = *(const f16x8*)(Bs + row * 128 + ((kk * 64 + lhi * 16) ^ ((row & 7) << 4)));
      }
#pragma unroll
      for (int i = 0; i < 4; ++i)
#pragma unroll
        for (int j = 0; j < 4; ++j) acc[i][j] = MFMA16(af[i], bf[j], acc[i][j]);
    }
    if (t + 1 < nsteps) writeB(nxt);
    __syncthreads();
  }

  const int gm = m0 + wm * 64, gn = n0 + wn * 64;
#pragma unroll
  for (int j = 0; j < 4; ++j) {
    int gcol = gn + j * 16 + l15;
    float bj = bias ? bias[gcol] : 0.f;
    float lb0 = 0.f, lb1 = 0.f, lb2 = 0.f, lb3 = 0.f;
    if (loraB) {
      const float* p = loraB + (size_t)gcol * 4;
      lb0 = p[0]; lb1 = p[1]; lb2 = p[2]; lb3 = p[3];
    }
#pragma unroll
    for (int i = 0; i < 4; ++i) {
      float v4[4];
#pragma unroll
      for (int r = 0; r < 4; ++r) {
        int grow = gm + i * 16 + lhi * 4 + r;
        float val = acc[i][j][r] + bj;
        if (loraT) {
          const float* tp = loraT + (size_t)grow * 4;
          val += 0.25f * (tp[0] * lb0 + tp[1] * lb1 + tp[2] * lb2 + tp[3] * lb3);
        }
        if (dogelu) val = 0.5f * val * (1.0f + erff(val * 0.70710678118654752f));
        if (residf) val += residf[(size_t)grow * N + gcol];
        if (residb) val += (float)residb[(size_t)grow * N + gcol];
        v4[r] = val;
      }
      if (Cf) {
#pragma unroll
        for (int r = 0; r < 4; ++r)
          Cf[(size_t)(gm + i * 16 + lhi * 4 + r) * N + gcol] = v4[r];
      } else if (Cvt) {
        int grow0 = gm + i * 16 + lhi * 4;
        int bb = grow0 >> 10, ss = grow0 & 1023;
        int hh = gcol >> 6, dd = gcol & 63;
        f16x4 pk;
#pragma unroll
        for (int r = 0; r < 4; ++r) pk[r] = (f16_t)v4[r];
        *(f16x4*)(Cvt + (((size_t)bb * 16 + hh) * 64 + dd) * 1024 + ss) = pk;
      } else {
#pragma unroll
        for (int r = 0; r < 4; ++r)
          Cb[(size_t)(gm + i * 16 + lhi * 4 + r) * N + gcol] = (f16_t)v4[r];
      }
    }
  }
}

// ---------------------------------------------------------------------------
// Flash attention, MFMA (PROVEN version: 90.4-91.7 us across R3/R6/R8).
// One block = (b, h, 128 q-rows). 4 waves; wave w owns q-rows w*32..+31.
// K/V tiles of 64 keys; V pre-transposed vt[b][h][d][s]. Online softmax via
// swizzled f16 LDS (2 lanes/row, 32 keys each). Scale 0.125 = hd^-0.5.
// ---------------------------------------------------------------------------
__global__ __launch_bounds__(256, 3) void attn_mfma(const f16_t* __restrict__ q,
                                                    const f16_t* __restrict__ k,
                                                    const f16_t* __restrict__ vt,
                                                    f16_t* __restrict__ wv) {
  const int S = 1024, D = 1024;
  __shared__ __align__(16) f16_t Qs[128 * 64];
  __shared__ __align__(16) f16_t SP[128 * 64];
  __shared__ __align__(16) f16_t Ks[64 * 64];
  __shared__ __align__(16) f16_t Vts[64 * 64];
  __shared__ float rsb[128];
  __shared__ float lib[128];
  const int tid = threadIdx.x, lane = tid & 63, w = tid >> 6;
  const int l15 = lane & 15, lhi = lane >> 4;
  const int q0 = blockIdx.x * 128;
  const int h = blockIdx.y, b = blockIdx.z;
  const f16_t* qg = q + ((size_t)b * S + q0) * D + h * 64;
  const f16_t* kg = k + (size_t)b * S * D + h * 64;
  const f16_t* vg = vt + ((size_t)b * 16 + h) * 64 * (size_t)S;

  // stage Q tile (swizzled rows of 128 B)
#pragma unroll
  for (int c = 0; c < 4; ++c) {
    int r = c * 32 + (tid >> 3), kc = tid & 7;
    f16x8 xx = *(const f16x8*)(qg + (size_t)r * D + kc * 8);
    *(f16x8*)((char*)Qs + r * 128 + ((kc * 16) ^ ((r & 7) << 4))) = xx;
  }
  __syncthreads();
  // hoist Q fragments
  f16x8 qf[2][2];
#pragma unroll
  for (int i = 0; i < 2; ++i) {
    int row = w * 32 + i * 16 + l15;
#pragma unroll
    for (int kk = 0; kk < 2; ++kk)
      qf[i][kk] = *(const f16x8*)((char*)Qs + row * 128 +
                                  ((kk * 64 + lhi * 16) ^ ((row & 7) << 4)));
  }

  f32x4 oacc[2][4];
#pragma unroll
  for (int i = 0; i < 2; ++i)
#pragma unroll
    for (int j = 0; j < 4; ++j) oacc[i][j] = (f32x4){0.f, 0.f, 0.f, 0.f};
  float m_run = -1e30f, l_run = 0.f;
  const int myrow = w * 32 + (lane >> 1);
  const int half = lane & 1;

  for (int kv = 0; kv < 16; ++kv) {
    __syncthreads();  // K/V/SP safe to overwrite
#pragma unroll
    for (int c = 0; c < 2; ++c) {
      int r = c * 32 + (tid >> 3), kc = tid & 7;
      f16x8 xk = *(const f16x8*)(kg + (size_t)(kv * 64 + r) * D + kc * 8);
      *(f16x8*)((char*)Ks + r * 128 + ((kc * 16) ^ ((r & 7) << 4))) = xk;
      f16x8 xv = *(const f16x8*)(vg + (size_t)r * S + kv * 64 + kc * 8);
      *(f16x8*)((char*)Vts + r * 128 + ((kc * 16) ^ ((r & 7) << 4))) = xv;
    }
    __syncthreads();
    // QK^T
    f32x4 sacc[2][4];
#pragma unroll
    for (int i = 0; i < 2; ++i)
#pragma unroll
      for (int j = 0; j < 4; ++j) sacc[i][j] = (f32x4){0.f, 0.f, 0.f, 0.f};
#pragma unroll
    for (int kk = 0; kk < 2; ++kk) {
      f16x8 kf[4];
#pragma unroll
      for (int j = 0; j < 4; ++j) {
        int row = j * 16 + l15;
        kf[j] = *(const f16x8*)((char*)Ks + row * 128 +
                                ((kk * 64 + lhi * 16) ^ ((row & 7) << 4)));
      }
#pragma unroll
      for (int i = 0; i < 2; ++i)
#pragma unroll
        for (int j = 0; j < 4; ++j) sacc[i][j] = MFMA16(qf[i][kk], kf[j], sacc[i][j]);
    }
    // scatter scaled scores to SP (f16, swizzled)
#pragma unroll
    for (int i = 0; i < 2; ++i)
#pragma unroll
      for (int j = 0; j < 4; ++j)
#pragma unroll
        for (int r = 0; r < 4; ++r) {
          int srow = w * 32 + i * 16 + lhi * 4 + r;
          int scol = j * 16 + l15;
          *(f16_t*)((char*)SP + srow * 128 + ((scol * 2) ^ ((srow & 7) << 4))) =
              (f16_t)(sacc[i][j][r] * 0.125f);
        }
    __syncthreads();
    // online softmax: 2 lanes per row, 32 keys each; exp in place -> P
    f16x8 ch[4];
#pragma unroll
    for (int c = 0; c < 4; ++c)
      ch[c] = *(const f16x8*)((char*)SP + myrow * 128 +
                              ((half * 64 + c * 16) ^ ((myrow & 7) << 4)));
    float mt = -1e30f;
#pragma unroll
    for (int c = 0; c < 4; ++c)
#pragma unroll
      for (int e = 0; e < 8; ++e) mt = fmaxf(mt, (float)ch[c][e]);
    mt = fmaxf(mt, __shfl_xor(mt, 1));
    float mnew = fmaxf(m_run, mt);
    float resc = __expf(m_run - mnew);
    float lsum = 0.f;
#pragma unroll
    for (int c = 0; c < 4; ++c) {
      f16x8 p8;
#pragma unroll
      for (int e = 0; e < 8; ++e) {
        float p = __expf((float)ch[c][e] - mnew);
        lsum += p;
        p8[e] = (f16_t)p;
      }
      *(f16x8*)((char*)SP + myrow * 128 + ((half * 64 + c * 16) ^ ((myrow & 7) << 4))) = p8;
    }
    lsum += __shfl_xor(lsum, 1);
    l_run = l_run * resc + lsum;
    m_run = mnew;
    if (half == 0) rsb[myrow] = resc;
    __syncthreads();
    // rescale O accumulator, then PV
#pragma unroll
    for (int i = 0; i < 2; ++i) {
      float f0 = rsb[w * 32 + i * 16 + lhi * 4 + 0];
      float f1 = rsb[w * 32 + i * 16 + lhi * 4 + 1];
      float f2 = rsb[w * 32 + i * 16 + lhi * 4 + 2];
      float f3 = rsb[w * 32 + i * 16 + lhi * 4 + 3];
#pragma unroll
      for (int j = 0; j < 4; ++j) {
        oacc[i][j][0] *= f0;
        oacc[i][j][1] *= f1;
        oacc[i][j][2] *= f2;
        oacc[i][j][3] *= f3;
      }
    }
#pragma unroll
    for (int kk = 0; kk < 2; ++kk) {
      f16x8 pa[2], vb[4];
#pragma unroll
      for (int i = 0; i < 2; ++i) {
        int row = w * 32 + i * 16 + l15;
        pa[i] = *(const f16x8*)((char*)SP + row * 128 +
                                ((kk * 64 + lhi * 16) ^ ((row & 7) << 4)));
      }
#pragma unroll
      for (int j = 0; j < 4; ++j) {
        int row = j * 16 + l15;
        vb[j] = *(const f16x8*)((char*)Vts + row * 128 +
                                ((kk * 64 + lhi * 16) ^ ((row & 7) << 4)));
      }
#pragma unroll
      for (int i = 0; i < 2; ++i)
#pragma unroll
        for (int j = 0; j < 4; ++j) oacc[i][j] = MFMA16(pa[i], vb[j], oacc[i][j]);
    }
  }
  if (half == 0) lib[myrow] = 1.f / l_run;
  __syncthreads();
#pragma unroll
  for (int i = 0; i < 2; ++i)
#pragma unroll
    for (int r = 0; r < 4; ++r) {
      int row = w * 32 + i * 16 + lhi * 4 + r;
      float li = lib[row];
      size_t base = ((size_t)b * S + q0 + row) * D + h * 64;
#pragma unroll
      for (int j = 0; j < 4; ++j)
        wv[base + j * 16 + l15] = (f16_t)(oacc[i][j][r] * li);
    }
}

// ---------------------------------------------------------------------------
extern "C" void kernel_launch(void* const* d_in, const int* in_sizes, int n_in,
                              void* d_out, int out_size, void* d_ws, size_t ws_size,
                              hipStream_t stream) {
  const int B = 8, S = 1024, D = 1024, F = 4096;
  const int M = B * S;  // 8192

  const float* x = (const float*)d_in[0];
  const float* Wq = (const float*)d_in[1];
  const float* bq = (const float*)d_in[2];
  const float* Wk = (const float*)d_in[3];
  const float* Wv = (const float*)d_in[4];
  const float* bv = (const float*)d_in[5];
  const float* Wo = (const float*)d_in[6];
  const float* bo = (const float*)d_in[7];
  const float* la_k = (const float*)d_in[8];
  const float* lb_k = (const float*)d_in[9];
  const float* la_v = (const float*)d_in[10];
  const float* lb_v = (const float*)d_in[11];
  const float* la_o = (const float*)d_in[12];
  const float* lb_o = (const float*)d_in[13];
  const float* g_attn = (const float*)d_in[14];
  const float* b_attn = (const float*)d_in[15];
  const float* W1 = (const float*)d_in[16];
  const float* b1 = (const float*)d_in[17];
  const float* W2 = (const float*)d_in[18];
  const float* b2 = (const float*)d_in[19];
  const float* g_mlp = (const float*)d_in[20];
  const float* b_mlp = (const float*)d_in[21];

  // ---- workspace layout ----
  // [16B pad][t_k][t_v][t_o fp32, ~384KB] [P0][P1][P2][P3] (16 MiB each, f16)
  // [Wqkvf 3D*D][Wof D*D][W1f F*D][W2f D*F] f16 weights (24 MiB total).
  float* t_k = (float*)((char*)d_ws + 16);
  float* t_v = t_k + (size_t)M * 4;
  float* t_o = t_v + (size_t)M * 4;
  const size_t MD = (size_t)M * D;
  f16_t* P0 = (f16_t*)((char*)d_ws + 409600);
  f16_t* P1 = P0 + MD;
  f16_t* P2 = P0 + 2 * MD;
  f16_t* P3 = P0 + 3 * MD;
  f16_t* Wqkvf = P0 + 4 * MD;                  // [3072,1024] f16
  f16_t* Wof = Wqkvf + 3 * (size_t)D * D;
  f16_t* W1f = Wof + (size_t)D * D;
  f16_t* W2f = W1f + (size_t)F * D;
  float* outf = (float*)d_out;
  const size_t need = 409600 + 4 * MD * sizeof(f16_t) +
                      (4 * (size_t)D * D + 2 * (size_t)F * D) * sizeof(f16_t);
  const bool f16w = ws_size >= need;

  if (f16w)
    convert_w<<<6144, 256, 0, stream>>>(
        Wq, Wk, Wv, Wo, W1, W2, Wqkvf, Wqkvf + (size_t)D * D,
        Wqkvf + 2 * (size_t)D * D, Wof, W1f, W2f);

  // 1+2. h = LN(x) -> P0, fused with LoRA t_k/t_v
  ln_lora_f32<<<M, 256, 0, stream>>>(x, g_attn, b_attn, la_k, la_v, P0, t_k, t_v);
  // 3. fused QKV projection: q -> P1, k -> P2, v -> P3 ([B,H,64,S] transposed)
  if (f16w) {
    gemm_qkv_pipe<<<dim3(12, 64), 512, 0, stream>>>(
        P0, Wqkvf, bq, bv, t_k, lb_k, t_v, lb_v, P1, P2, P3, D);
  } else {
    gemm_mfma<<<dim3(8, 64), 256, 0, stream>>>(
        P0, Wq, bq, nullptr, nullptr, nullptr, nullptr, P1, nullptr, nullptr,
        M, D, D, D, 0);
    gemm_mfma<<<dim3(8, 64), 256, 0, stream>>>(
        P0, Wk, nullptr, t_k, lb_k, nullptr, nullptr, P2, nullptr, nullptr,
        M, D, D, D, 0);
    gemm_mfma<<<dim3(8, 64), 256, 0, stream>>>(
        P0, Wv, bv, t_v, lb_v, nullptr, nullptr, nullptr, nullptr, P3,
        M, D, D, D, 0);
  }
  // 4. attention -> wv (f16) -> P0 (h dead); proven 128-q-row blocks
  attn_mfma<<<dim3(8, 16, 8), 256, 0, stream>>>(P1, P2, P3, P0);
  // 5. LoRA t for o (input wv)
  lora_t_kernel<<<M / 4, 256, 0, stream>>>(P0, la_o, t_o, D);
  // 6. x1 = x + wv @ Wo^T + bo + lora_o -> P3 (f16; q/k/Vt dead)
  if (f16w)
    gemm_pipe<<<dim3(4, 64), 512, 0, stream>>>(
        P0, Wof, bo, t_o, lb_o, x, nullptr, P3, nullptr, M, D, D, D, 0);
  else
    gemm_mfma<<<dim3(8, 64), 256, 0, stream>>>(
        P0, Wo, bo, t_o, lb_o, x, nullptr, P3, nullptr, nullptr, M, D, D, D, 0);
  // 7. h2 = LN(x1) -> P0 (wv dead)
  ln_f16<<<M, 256, 0, stream>>>(P3, g_mlp, b_mlp, P0);
  // 8/9. MLP in two N=2048 halves: u -> P1∪P2, out accumulates on d_out (f32)
  if (f16w) {
    gemm_pipe<<<dim3(8, 64), 512, 0, stream>>>(
        P0, W1f, b1, nullptr, nullptr, nullptr, nullptr, P1, nullptr,
        M, 2048, D, D, 1);
    gemm_pipe<<<dim3(4, 64), 512, 0, stream>>>(
        P1, W2f, b2, nullptr, nullptr, nullptr, P3, nullptr, outf,
        M, D, 2048, F, 0);
    gemm_pipe<<<dim3(8, 64), 512, 0, stream>>>(
        P0, W1f + (size_t)2048 * D, b1 + 2048, nullptr, nullptr, nullptr, nullptr,
        P1, nullptr, M, 2048, D, D, 1);
    gemm_pipe<<<dim3(4, 64), 512, 0, stream>>>(
        P1, W2f + 2048, nullptr, nullptr, nullptr, outf, nullptr, nullptr, outf,
        M, D, 2048, F, 0);
  } else {
    gemm_mfma<<<dim3(16, 64), 256, 0, stream>>>(
        P0, W1, b1, nullptr, nullptr, nullptr, nullptr, P1, nullptr, nullptr,
        M, 2048, D, D, 1);
    gemm_mfma<<<dim3(8, 64), 256, 0, stream>>>(
        P1, W2, b2, nullptr, nullptr, nullptr, P3, nullptr, outf, nullptr,
        M, D, 2048, F, 0);
    gemm_mfma<<<dim3(16, 64), 256, 0, stream>>>(
        P0, W1 + (size_t)2048 * D, b1 + 2048, nullptr, nullptr, nullptr, nullptr,
        P1, nullptr, nullptr, M, 2048, D, D, 1);
    gemm_mfma<<<dim3(8, 64), 256, 0, stream>>>(
        P1, W2 + 2048, nullptr, nullptr, nullptr, outf, nullptr, nullptr, outf,
        nullptr, M, D, 2048, F, 0);
  }
}

// Round 15
// 642.978 us; speedup vs baseline: 1.3362x; 1.0268x over previous
//
#include <hip/hip_runtime.h>
#include <math.h>

typedef _Float16 f16_t;
typedef f16_t f16x8 __attribute__((ext_vector_type(8)));
typedef f16_t f16x4 __attribute__((ext_vector_type(4)));
typedef float f32x4 __attribute__((ext_vector_type(4)));
typedef float fv4 __attribute__((ext_vector_type(4)));

#define MFMA16(a, b, c) __builtin_amdgcn_mfma_f32_16x16x32_f16(a, b, c, 0, 0, 0)

__device__ __forceinline__ void gload16(const void* g, void* l) {
  __builtin_amdgcn_global_load_lds((const __attribute__((address_space(1))) void*)g,
                                   (__attribute__((address_space(3))) void*)l, 16, 0, 0);
}

// ---------------------------------------------------------------------------
// LayerNorm, fp32 input -> f16 output. One 256-thread block per row of 1024.
// (R8 configuration: separate LN and LoRA-kv kernels -- the fused variant
// measured +13.5 us in R14 and was reverted.)
// ---------------------------------------------------------------------------
__global__ __launch_bounds__(256) void ln_f32(const float* __restrict__ x,
                                              const float* __restrict__ g,
                                              const float* __restrict__ b,
                                              f16_t* __restrict__ y) {
  const int D = 1024;
  int row = blockIdx.x;
  int t = threadIdx.x;
  const float* xr = x + (size_t)row * D + t * 4;
  float x0 = xr[0], x1 = xr[1], x2 = xr[2], x3 = xr[3];
  float sum = x0 + x1 + x2 + x3;
  float sq = x0 * x0 + x1 * x1 + x2 * x2 + x3 * x3;
  for (int d = 32; d; d >>= 1) {
    sum += __shfl_down(sum, d);
    sq += __shfl_down(sq, d);
  }
  __shared__ float ssum[4], ssq[4];
  int w = t >> 6, lane = t & 63;
  if (lane == 0) { ssum[w] = sum; ssq[w] = sq; }
  __syncthreads();
  float ts = ssum[0] + ssum[1] + ssum[2] + ssum[3];
  float tq = ssq[0] + ssq[1] + ssq[2] + ssq[3];
  float mean = ts * (1.0f / 1024.0f);
  float var = tq * (1.0f / 1024.0f) - mean * mean;
  float rstd = rsqrtf(var + 1e-5f);
  f16_t* yr = y + (size_t)row * D + t * 4;
  const float* gr = g + t * 4;
  const float* br = b + t * 4;
  yr[0] = (f16_t)((x0 - mean) * rstd * gr[0] + br[0]);
  yr[1] = (f16_t)((x1 - mean) * rstd * gr[1] + br[1]);
  yr[2] = (f16_t)((x2 - mean) * rstd * gr[2] + br[2]);
  yr[3] = (f16_t)((x3 - mean) * rstd * gr[3] + br[3]);
}

// LayerNorm, f16 input -> f16 output.
__global__ __launch_bounds__(256) void ln_f16(const f16_t* __restrict__ x,
                                              const float* __restrict__ g,
                                              const float* __restrict__ b,
                                              f16_t* __restrict__ y) {
  const int D = 1024;
  int row = blockIdx.x;
  int t = threadIdx.x;
  const f16_t* xr = x + (size_t)row * D + t * 4;
  float x0 = (float)xr[0], x1 = (float)xr[1], x2 = (float)xr[2], x3 = (float)xr[3];
  float sum = x0 + x1 + x2 + x3;
  float sq = x0 * x0 + x1 * x1 + x2 * x2 + x3 * x3;
  for (int d = 32; d; d >>= 1) {
    sum += __shfl_down(sum, d);
    sq += __shfl_down(sq, d);
  }
  __shared__ float ssum[4], ssq[4];
  int w = t >> 6, lane = t & 63;
  if (lane == 0) { ssum[w] = sum; ssq[w] = sq; }
  __syncthreads();
  float ts = ssum[0] + ssum[1] + ssum[2] + ssum[3];
  float tq = ssq[0] + ssq[1] + ssq[2] + ssq[3];
  float mean = ts * (1.0f / 1024.0f);
  float var = tq * (1.0f / 1024.0f) - mean * mean;
  float rstd = rsqrtf(var + 1e-5f);
  f16_t* yr = y + (size_t)row * D + t * 4;
  const float* gr = g + t * 4;
  const float* br = b + t * 4;
  yr[0] = (f16_t)((x0 - mean) * rstd * gr[0] + br[0]);
  yr[1] = (f16_t)((x1 - mean) * rstd * gr[1] + br[1]);
  yr[2] = (f16_t)((x2 - mean) * rstd * gr[2] + br[2]);
  yr[3] = (f16_t)((x3 - mean) * rstd * gr[3] + br[3]);
}

// ---------------------------------------------------------------------------
// Weight convert fp32 -> f16, one fused launch for all 6 matrices.
// (q/k/v write into one contiguous [3072,1024] blob via the o* pointers.)
// ---------------------------------------------------------------------------
__global__ __launch_bounds__(256) void convert_w(
    const float* __restrict__ wq, const float* __restrict__ wk,
    const float* __restrict__ wv, const float* __restrict__ wo,
    const float* __restrict__ w1, const float* __restrict__ w2,
    f16_t* __restrict__ oq, f16_t* __restrict__ ok, f16_t* __restrict__ ov,
    f16_t* __restrict__ oo, f16_t* __restrict__ o1, f16_t* __restrict__ o2) {
  int bid = blockIdx.x;
  const float* src;
  f16_t* dst;
  int bi;
  if (bid < 2048) {
    int seg = bid >> 9;
    bi = bid & 511;
    src = seg == 0 ? wq : seg == 1 ? wk : seg == 2 ? wv : wo;
    dst = seg == 0 ? oq : seg == 1 ? ok : seg == 2 ? ov : oo;
  } else if (bid < 4096) {
    bi = bid - 2048; src = w1; dst = o1;
  } else {
    bi = bid - 4096; src = w2; dst = o2;
  }
  size_t idx = (size_t)bi * 2048 + (size_t)threadIdx.x * 8;
  fv4 a = *(const fv4*)(src + idx);
  fv4 b = *(const fv4*)(src + idx + 4);
  f16x8 h;
#pragma unroll
  for (int j = 0; j < 4; ++j) { h[j] = (f16_t)a[j]; h[4 + j] = (f16_t)b[j]; }
  *(f16x8*)(dst + idx) = h;
}

// ---------------------------------------------------------------------------
// LoRA first stage for k AND v in one pass: t[M,4] = h[M,K] @ la[4,K]^T.
// One wave per row; h read once. (R8-proven.)
// ---------------------------------------------------------------------------
__global__ __launch_bounds__(256) void lora_kv_kernel(
    const f16_t* __restrict__ h, const float* __restrict__ la_k,
    const float* __restrict__ la_v, float* __restrict__ t_k,
    float* __restrict__ t_v, int K) {
  int lane = threadIdx.x & 63;
  int w = threadIdx.x >> 6;
  int row = blockIdx.x * 4 + w;
  const f16_t* hrow = h + (size_t)row * K;
  float ak[4] = {0.f, 0.f, 0.f, 0.f};
  float av[4] = {0.f, 0.f, 0.f, 0.f};
  for (int it = 0; it < K / 512; ++it) {
    int base = it * 512 + lane * 8;
    f16x8 hx = *(const f16x8*)(hrow + base);
#pragma unroll
    for (int r = 0; r < 4; ++r) {
      const float* kr = la_k + (size_t)r * K + base;
      const float* vr = la_v + (size_t)r * K + base;
#pragma unroll
      for (int j = 0; j < 8; ++j) {
        float hv = (float)hx[j];
        ak[r] += hv * kr[j];
        av[r] += hv * vr[j];
      }
    }
  }
#pragma unroll
  for (int r = 0; r < 4; ++r) {
    for (int d = 32; d; d >>= 1) {
      ak[r] += __shfl_down(ak[r], d);
      av[r] += __shfl_down(av[r], d);
    }
  }
  if (lane == 0) {
#pragma unroll
    for (int r = 0; r < 4; ++r) {
      t_k[(size_t)row * 4 + r] = ak[r];
      t_v[(size_t)row * 4 + r] = av[r];
    }
  }
}

// LoRA first stage, single matrix (o-projection).
__global__ __launch_bounds__(256) void lora_t_kernel(const f16_t* __restrict__ h,
                                                     const float* __restrict__ la,
                                                     float* __restrict__ t, int K) {
  int lane = threadIdx.x & 63;
  int w = threadIdx.x >> 6;
  int row = blockIdx.x * 4 + w;
  const f16_t* hrow = h + (size_t)row * K;
  float acc[4] = {0.f, 0.f, 0.f, 0.f};
  for (int it = 0; it < K / 512; ++it) {
    int base = it * 512 + lane * 8;
    f16x8 hx = *(const f16x8*)(hrow + base);
#pragma unroll
    for (int r = 0; r < 4; ++r) {
      const float* ar = la + (size_t)r * K + base;
#pragma unroll
      for (int j = 0; j < 8; ++j) acc[r] += (float)hx[j] * ar[j];
    }
  }
#pragma unroll
  for (int r = 0; r < 4; ++r) {
    for (int d = 32; d; d >>= 1) acc[r] += __shfl_down(acc[r], d);
  }
  if (lane == 0) {
#pragma unroll
    for (int r = 0; r < 4; ++r) t[(size_t)row * 4 + r] = acc[r];
  }
}

// ===========================================================================
// PIPELINED MFMA f16 GEMM core (R8-proven): 128x256 tile, BK=64, 512 threads,
// 3-deep LDS (144 KB), counted-vmcnt pipeline (never drains to 0 mid-loop).
// ===========================================================================
#define GEMM_PIPE_BODY                                                        \
  f32x4 acc[4][4];                                                            \
  _Pragma("unroll") for (int i = 0; i < 4; ++i)                               \
      _Pragma("unroll") for (int j = 0; j < 4; ++j)                           \
          acc[i][j] = (f32x4){0.f, 0.f, 0.f, 0.f};                            \
  const int nsteps = K >> 6;                                                  \
  stageA(0, 0); stageB(0, 0);                                                 \
  stageA(1, 1); stageB(1, 1);                                                 \
  stageA(2, 2); stageB(2, 2);                                                 \
  int b3 = 0;                                                                 \
  for (int kt = 0; kt < nsteps; ++kt) {                                       \
    if (kt + 2 < nsteps)                                                      \
      asm volatile("s_waitcnt vmcnt(12)" ::: "memory");                       \
    else if (kt + 1 < nsteps)                                                 \
      asm volatile("s_waitcnt vmcnt(6)" ::: "memory");                        \
    else                                                                      \
      asm volatile("s_waitcnt vmcnt(0)" ::: "memory");                        \
    __builtin_amdgcn_sched_barrier(0);                                        \
    __builtin_amdgcn_s_barrier();                                             \
    f16x8 af[4][2], bf[4][2];                                                 \
    _Pragma("unroll") for (int kk = 0; kk < 2; ++kk) {                        \
      _Pragma("unroll") for (int i = 0; i < 4; ++i) {                         \
        int row = wm * 64 + i * 16 + l15;                                     \
        af[i][kk] = *(const f16x8*)((const char*)Abuf[b3] + row * 128 +       \
                                    ((kk * 64 + lhi * 16) ^ ((row & 7) << 4)));\
      }                                                                       \
      _Pragma("unroll") for (int j = 0; j < 4; ++j) {                         \
        int row = wn * 64 + j * 16 + l15;                                     \
        bf[j][kk] = *(const f16x8*)((const char*)Bbuf[b3] + row * 128 +       \
                                    ((kk * 64 + lhi * 16) ^ ((row & 7) << 4)));\
      }                                                                       \
    }                                                                         \
    asm volatile("s_waitcnt lgkmcnt(0)" ::: "memory");                        \
    __builtin_amdgcn_sched_barrier(0);                                        \
    __builtin_amdgcn_s_barrier();                                             \
    if (kt + 3 < nsteps) { stageA(kt + 3, b3); stageB(kt + 3, b3); }          \
    __builtin_amdgcn_sched_barrier(0);                                        \
    __builtin_amdgcn_s_setprio(1);                                            \
    _Pragma("unroll") for (int kk = 0; kk < 2; ++kk)                          \
        _Pragma("unroll") for (int i = 0; i < 4; ++i)                         \
            _Pragma("unroll") for (int j = 0; j < 4; ++j)                     \
                acc[i][j] = MFMA16(af[i][kk], bf[j][kk], acc[i][j]);          \
    __builtin_amdgcn_s_setprio(0);                                            \
    b3 = (b3 == 2) ? 0 : b3 + 1;                                              \
  }

// ---------------------------------------------------------------------------
// Pipelined GEMM with generic epilogue.
// ---------------------------------------------------------------------------
__global__ __launch_bounds__(512, 2) void gemm_pipe(
    const f16_t* __restrict__ A, const f16_t* __restrict__ B,
    const float* __restrict__ bias, const float* __restrict__ loraT,
    const float* __restrict__ loraB, const float* residf,
    const f16_t* __restrict__ residb, f16_t* Cb, float* Cf,
    int M, int N, int K, int ldb, int dogelu) {
  __shared__ __align__(16) f16_t Abuf[3][8192];
  __shared__ __align__(16) f16_t Bbuf[3][16384];
  const int tid = threadIdx.x;
  const int lane = tid & 63, wid = tid >> 6;
  const int wm = wid >> 2, wn = wid & 3;
  const int l15 = lane & 15, lhi = lane >> 4;
  int nwg = gridDim.x * gridDim.y;
  int bid = blockIdx.y * gridDim.x + blockIdx.x;
  int swz = (bid & 7) * (nwg >> 3) + (bid >> 3);
  const int m0 = (swz / gridDim.x) * 128, n0 = (swz % gridDim.x) * 256;
  const int arow = tid >> 3;
  const int aslot = tid & 7;

  auto stageA = [&](int step, int buf) {
#pragma unroll
    for (int c = 0; c < 2; ++c) {
      int r = c * 64 + arow;
      int cm = aslot ^ (r & 7);
      gload16(A + (size_t)(m0 + r) * K + (size_t)step * 64 + cm * 8,
              (char*)Abuf[buf] + c * 8192 + wid * 1024);
    }
  };
  auto stageB = [&](int step, int buf) {
#pragma unroll
    for (int c = 0; c < 4; ++c) {
      int r = c * 64 + arow;
      int cm = aslot ^ (r & 7);
      gload16(B + (size_t)(n0 + r) * ldb + (size_t)step * 64 + cm * 8,
              (char*)Bbuf[buf] + c * 8192 + wid * 1024);
    }
  };

  GEMM_PIPE_BODY

  const int gm = m0 + wm * 64, gn = n0 + wn * 64;
#pragma unroll
  for (int j = 0; j < 4; ++j) {
    int gcol = gn + j * 16 + l15;
    float bj = bias ? bias[gcol] : 0.f;
    float lb0 = 0.f, lb1 = 0.f, lb2 = 0.f, lb3 = 0.f;
    if (loraB) {
      const float* p = loraB + (size_t)gcol * 4;
      lb0 = p[0]; lb1 = p[1]; lb2 = p[2]; lb3 = p[3];
    }
#pragma unroll
    for (int i = 0; i < 4; ++i) {
      float v4[4];
#pragma unroll
      for (int r = 0; r < 4; ++r) {
        int grow = gm + i * 16 + lhi * 4 + r;
        float val = acc[i][j][r] + bj;
        if (loraT) {
          const float* tp = loraT + (size_t)grow * 4;
          val += 0.25f * (tp[0] * lb0 + tp[1] * lb1 + tp[2] * lb2 + tp[3] * lb3);
        }
        if (dogelu) val = 0.5f * val * (1.0f + erff(val * 0.70710678118654752f));
        if (residf) val += residf[(size_t)grow * N + gcol];
        if (residb) val += (float)residb[(size_t)grow * N + gcol];
        v4[r] = val;
      }
      if (Cf) {
#pragma unroll
        for (int r = 0; r < 4; ++r)
          Cf[(size_t)(gm + i * 16 + lhi * 4 + r) * N + gcol] = v4[r];
      } else {
#pragma unroll
        for (int r = 0; r < 4; ++r)
          Cb[(size_t)(gm + i * 16 + lhi * 4 + r) * N + gcol] = (f16_t)v4[r];
      }
    }
  }
}

// ---------------------------------------------------------------------------
// Pipelined fused QKV GEMM (R8-proven).
// ---------------------------------------------------------------------------
__global__ __launch_bounds__(512, 2) void gemm_qkv_pipe(
    const f16_t* __restrict__ A, const f16_t* __restrict__ W,
    const float* __restrict__ bq, const float* __restrict__ bv,
    const float* __restrict__ t_k, const float* __restrict__ lb_k,
    const float* __restrict__ t_v, const float* __restrict__ lb_v,
    f16_t* __restrict__ Pq, f16_t* __restrict__ Pk, f16_t* __restrict__ Pvt,
    int K) {
  const int D = 1024;
  __shared__ __align__(16) f16_t Abuf[3][8192];
  __shared__ __align__(16) f16_t Bbuf[3][16384];
  const int tid = threadIdx.x;
  const int lane = tid & 63, wid = tid >> 6;
  const int wm = wid >> 2, wn = wid & 3;
  const int l15 = lane & 15, lhi = lane >> 4;
  int nwg = gridDim.x * gridDim.y;
  int bid = blockIdx.y * gridDim.x + blockIdx.x;
  int swz = (bid & 7) * (nwg >> 3) + (bid >> 3);
  const int m0 = (swz / gridDim.x) * 128, n0 = (swz % gridDim.x) * 256;
  const int seg = n0 >> 10;
  const int arow = tid >> 3;
  const int aslot = tid & 7;

  auto stageA = [&](int step, int buf) {
#pragma unroll
    for (int c = 0; c < 2; ++c) {
      int r = c * 64 + arow;
      int cm = aslot ^ (r & 7);
      gload16(A + (size_t)(m0 + r) * K + (size_t)step * 64 + cm * 8,
              (char*)Abuf[buf] + c * 8192 + wid * 1024);
    }
  };
  auto stageB = [&](int step, int buf) {
#pragma unroll
    for (int c = 0; c < 4; ++c) {
      int r = c * 64 + arow;
      int cm = aslot ^ (r & 7);
      gload16(W + (size_t)(n0 + r) * K + (size_t)step * 64 + cm * 8,
              (char*)Bbuf[buf] + c * 8192 + wid * 1024);
    }
  };

  GEMM_PIPE_BODY

  const int gm = m0 + wm * 64, gn = n0 + wn * 64;
  const float* tB = (seg == 1) ? t_k : t_v;
#pragma unroll
  for (int j = 0; j < 4; ++j) {
    int gcol = gn + j * 16 + l15;
    int c = gcol & 1023;
    float bj = (seg == 0) ? bq[c] : (seg == 2 ? bv[c] : 0.f);
    float lb0 = 0.f, lb1 = 0.f, lb2 = 0.f, lb3 = 0.f;
    if (seg) {
      const float* p = (seg == 1 ? lb_k : lb_v) + (size_t)c * 4;
      lb0 = p[0]; lb1 = p[1]; lb2 = p[2]; lb3 = p[3];
    }
#pragma unroll
    for (int i = 0; i < 4; ++i) {
      float v4[4];
#pragma unroll
      for (int r = 0; r < 4; ++r) {
        int grow = gm + i * 16 + lhi * 4 + r;
        float val = acc[i][j][r] + bj;
        if (seg) {
          const float* tp = tB + (size_t)grow * 4;
          val += 0.25f * (tp[0] * lb0 + tp[1] * lb1 + tp[2] * lb2 + tp[3] * lb3);
        }
        v4[r] = val;
      }
      if (seg < 2) {
        f16_t* dst = (seg == 0) ? Pq : Pk;
#pragma unroll
        for (int r = 0; r < 4; ++r)
          dst[(size_t)(gm + i * 16 + lhi * 4 + r) * D + c] = (f16_t)v4[r];
      } else {
        int grow0 = gm + i * 16 + lhi * 4;
        int bb = grow0 >> 10, ss = grow0 & 1023;
        int hh = c >> 6, dd = c & 63;
        f16x4 pk;
#pragma unroll
        for (int r = 0; r < 4; ++r) pk[r] = (f16_t)v4[r];
        *(f16x4*)(Pvt + (((size_t)bb * 16 + hh) * 64 + dd) * 1024 + ss) = pk;
      }
    }
  }
}

// ---------------------------------------------------------------------------
// Fallback GEMM (B fp32, reg-staged + converted); used only when ws_size
// can't hold f16 weights. Full epilogue incl. transposed-V output.
// ---------------------------------------------------------------------------
__global__ __launch_bounds__(256, 2) void gemm_mfma(
    const f16_t* __restrict__ A, const float* __restrict__ B,
    const float* __restrict__ bias, const float* __restrict__ loraT,
    const float* __restrict__ loraB, const float* residf,
    const f16_t* __restrict__ residb, f16_t* Cb, float* Cf, f16_t* Cvt,
    int M, int N, int K, int ldb, int dogelu) {
  __shared__ __align__(16) f16_t smem[2][16384];
  const int tid = threadIdx.x;
  const int lane = tid & 63, wid = tid >> 6;
  const int wm = wid >> 1, wn = wid & 1;
  const int l15 = lane & 15, lhi = lane >> 4;
  const int m0 = blockIdx.y * 128, n0 = blockIdx.x * 128;
  const int arow = tid >> 3;
  const int aslot = tid & 7;

  f32x4 acc[4][4];
#pragma unroll
  for (int i = 0; i < 4; ++i)
#pragma unroll
    for (int j = 0; j < 4; ++j) acc[i][j] = (f32x4){0.f, 0.f, 0.f, 0.f};

  fv4 breg[4][2];

  auto stageA = [&](int step, int buf) {
#pragma unroll
    for (int c = 0; c < 4; ++c) {
      int r = c * 32 + arow;
      int cm = aslot ^ (r & 7);
      gload16(A + (size_t)(m0 + r) * K + (size_t)step * 64 + cm * 8,
              (char*)&smem[buf][0] + c * 4096 + wid * 1024);
    }
  };
  auto loadB = [&](int step) {
#pragma unroll
    for (int c = 0; c < 4; ++c) {
      int r = c * 32 + arow;
      const float* gp = B + (size_t)(n0 + r) * ldb + (size_t)step * 64 + aslot * 8;
      breg[c][0] = *(const fv4*)gp;
      breg[c][1] = *(const fv4*)(gp + 4);
    }
  };
  auto writeB = [&](int buf) {
#pragma unroll
    for (int c = 0; c < 4; ++c) {
      int r = c * 32 + arow;
      f16x8 hh;
#pragma unroll
      for (int j = 0; j < 4; ++j) hh[j] = (f16_t)breg[c][0][j];
#pragma unroll
      for (int j = 0; j < 4; ++j) hh[4 + j] = (f16_t)breg[c][1][j];
      int boff = r * 128 + ((aslot * 16) ^ ((r & 7) << 4));
      *(f16x8*)((char*)&smem[buf][8192] + boff) = hh;
    }
  };

  const int nsteps = K >> 6;
  stageA(0, 0);
  loadB(0);
  writeB(0);
  __syncthreads();
  for (int t = 0; t < nsteps; ++t) {
    int cur = t & 1, nxt = cur ^ 1;
    if (t + 1 < nsteps) { stageA(t + 1, nxt); loadB(t + 1); }
    const char* As = (const char*)&smem[cur][0];
    const char* Bs = (const char*)&smem[cur][8192];
#pragma unroll
    for (int kk = 0; kk < 2; ++kk) {
      f16x8 af[4], bf[4];
#pragma unroll
      for (int i = 0; i < 4; ++i) {
        int row = wm * 64 + i * 16 + l15;
        af[i] = *(const f16x8*)(As + row * 128 + ((kk * 64 + lhi * 16) ^ ((row & 7) << 4)));
      }
#pragma unroll
      for (int j = 0; j < 4; ++j) {
        int row = wn * 64 + j * 16 + l15;
        bf[j] = *(const f16x8*)(Bs + row * 128 + ((kk * 64 + lhi * 16) ^ ((row & 7) << 4)));
      }
#pragma unroll
      for (int i = 0; i < 4; ++i)
#pragma unroll
        for (int j = 0; j < 4; ++j) acc[i][j] = MFMA16(af[i], bf[j], acc[i][j]);
    }
    if (t + 1 < nsteps) writeB(nxt);
    __syncthreads();
  }

  const int gm = m0 + wm * 64, gn = n0 + wn * 64;
#pragma unroll
  for (int j = 0; j < 4; ++j) {
    int gcol = gn + j * 16 + l15;
    float bj = bias ? bias[gcol] : 0.f;
    float lb0 = 0.f, lb1 = 0.f, lb2 = 0.f, lb3 = 0.f;
    if (loraB) {
      const float* p = loraB + (size_t)gcol * 4;
      lb0 = p[0]; lb1 = p[1]; lb2 = p[2]; lb3 = p[3];
    }
#pragma unroll
    for (int i = 0; i < 4; ++i) {
      float v4[4];
#pragma unroll
      for (int r = 0; r < 4; ++r) {
        int grow = gm + i * 16 + lhi * 4 + r;
        float val = acc[i][j][r] + bj;
        if (loraT) {
          const float* tp = loraT + (size_t)grow * 4;
          val += 0.25f * (tp[0] * lb0 + tp[1] * lb1 + tp[2] * lb2 + tp[3] * lb3);
        }
        if (dogelu) val = 0.5f * val * (1.0f + erff(val * 0.70710678118654752f));
        if (residf) val += residf[(size_t)grow * N + gcol];
        if (residb) val += (float)residb[(size_t)grow * N + gcol];
        v4[r] = val;
      }
      if (Cf) {
#pragma unroll
        for (int r = 0; r < 4; ++r)
          Cf[(size_t)(gm + i * 16 + lhi * 4 + r) * N + gcol] = v4[r];
      } else if (Cvt) {
        int grow0 = gm + i * 16 + lhi * 4;
        int bb = grow0 >> 10, ss = grow0 & 1023;
        int hh = gcol >> 6, dd = gcol & 63;
        f16x4 pk;
#pragma unroll
        for (int r = 0; r < 4; ++r) pk[r] = (f16_t)v4[r];
        *(f16x4*)(Cvt + (((size_t)bb * 16 + hh) * 64 + dd) * 1024 + ss) = pk;
      } else {
#pragma unroll
        for (int r = 0; r < 4; ++r)
          Cb[(size_t)(gm + i * 16 + lhi * 4 + r) * N + gcol] = (f16_t)v4[r];
      }
    }
  }
}

// ---------------------------------------------------------------------------
// Flash attention, MFMA (proven structure: 90.4-91.7 us across R3/R6/R8),
// plus T5 s_setprio around the two MFMA clusters (catalog: attn +4-7%,
// within-probe verified; attn blocks are independent so waves sit at
// different phases -- setprio lets the CU scheduler favor MFMA waves).
// One block = (b, h, 128 q-rows). 4 waves; wave w owns q-rows w*32..+31.
// K/V tiles of 64 keys; V pre-transposed vt[b][h][d][s]. Online softmax via
// swizzled f16 LDS (2 lanes/row, 32 keys each). Scale 0.125 = hd^-0.5.
// ---------------------------------------------------------------------------
__global__ __launch_bounds__(256, 3) void attn_mfma(const f16_t* __restrict__ q,
                                                    const f16_t* __restrict__ k,
                                                    const f16_t* __restrict__ vt,
                                                    f16_t* __restrict__ wv) {
  const int S = 1024, D = 1024;
  __shared__ __align__(16) f16_t Qs[128 * 64];
  __shared__ __align__(16) f16_t SP[128 * 64];
  __shared__ __align__(16) f16_t Ks[64 * 64];
  __shared__ __align__(16) f16_t Vts[64 * 64];
  __shared__ float rsb[128];
  __shared__ float lib[128];
  const int tid = threadIdx.x, lane = tid & 63, w = tid >> 6;
  const int l15 = lane & 15, lhi = lane >> 4;
  const int q0 = blockIdx.x * 128;
  const int h = blockIdx.y, b = blockIdx.z;
  const f16_t* qg = q + ((size_t)b * S + q0) * D + h * 64;
  const f16_t* kg = k + (size_t)b * S * D + h * 64;
  const f16_t* vg = vt + ((size_t)b * 16 + h) * 64 * (size_t)S;

  // stage Q tile (swizzled rows of 128 B)
#pragma unroll
  for (int c = 0; c < 4; ++c) {
    int r = c * 32 + (tid >> 3), kc = tid & 7;
    f16x8 xx = *(const f16x8*)(qg + (size_t)r * D + kc * 8);
    *(f16x8*)((char*)Qs + r * 128 + ((kc * 16) ^ ((r & 7) << 4))) = xx;
  }
  __syncthreads();
  // hoist Q fragments
  f16x8 qf[2][2];
#pragma unroll
  for (int i = 0; i < 2; ++i) {
    int row = w * 32 + i * 16 + l15;
#pragma unroll
    for (int kk = 0; kk < 2; ++kk)
      qf[i][kk] = *(const f16x8*)((char*)Qs + row * 128 +
                                  ((kk * 64 + lhi * 16) ^ ((row & 7) << 4)));
  }

  f32x4 oacc[2][4];
#pragma unroll
  for (int i = 0; i < 2; ++i)
#pragma unroll
    for (int j = 0; j < 4; ++j) oacc[i][j] = (f32x4){0.f, 0.f, 0.f, 0.f};
  float m_run = -1e30f, l_run = 0.f;
  const int myrow = w * 32 + (lane >> 1);
  const int half = lane & 1;

  for (int kv = 0; kv < 16; ++kv) {
    __syncthreads();  // K/V/SP safe to overwrite
#pragma unroll
    for (int c = 0; c < 2; ++c) {
      int r = c * 32 + (tid >> 3), kc = tid & 7;
      f16x8 xk = *(const f16x8*)(kg + (size_t)(kv * 64 + r) * D + kc * 8);
      *(f16x8*)((char*)Ks + r * 128 + ((kc * 16) ^ ((r & 7) << 4))) = xk;
      f16x8 xv = *(const f16x8*)(vg + (size_t)r * S + kv * 64 + kc * 8);
      *(f16x8*)((char*)Vts + r * 128 + ((kc * 16) ^ ((r & 7) << 4))) = xv;
    }
    __syncthreads();
    // QK^T
    f32x4 sacc[2][4];
#pragma unroll
    for (int i = 0; i < 2; ++i)
#pragma unroll
      for (int j = 0; j < 4; ++j) sacc[i][j] = (f32x4){0.f, 0.f, 0.f, 0.f};
    __builtin_amdgcn_s_setprio(1);
#pragma unroll
    for (int kk = 0; kk < 2; ++kk) {
      f16x8 kf[4];
#pragma unroll
      for (int j = 0; j < 4; ++j) {
        int row = j * 16 + l15;
        kf[j] = *(const f16x8*)((char*)Ks + row * 128 +
                                ((kk * 64 + lhi * 16) ^ ((row & 7) << 4)));
      }
#pragma unroll
      for (int i = 0; i < 2; ++i)
#pragma unroll
        for (int j = 0; j < 4; ++j) sacc[i][j] = MFMA16(qf[i][kk], kf[j], sacc[i][j]);
    }
    __builtin_amdgcn_s_setprio(0);
    // scatter scaled scores to SP (f16, swizzled)
#pragma unroll
    for (int i = 0; i < 2; ++i)
#pragma unroll
      for (int j = 0; j < 4; ++j)
#pragma unroll
        for (int r = 0; r < 4; ++r) {
          int srow = w * 32 + i * 16 + lhi * 4 + r;
          int scol = j * 16 + l15;
          *(f16_t*)((char*)SP + srow * 128 + ((scol * 2) ^ ((srow & 7) << 4))) =
              (f16_t)(sacc[i][j][r] * 0.125f);
        }
    __syncthreads();
    // online softmax: 2 lanes per row, 32 keys each; exp in place -> P
    f16x8 ch[4];
#pragma unroll
    for (int c = 0; c < 4; ++c)
      ch[c] = *(const f16x8*)((char*)SP + myrow * 128 +
                              ((half * 64 + c * 16) ^ ((myrow & 7) << 4)));
    float mt = -1e30f;
#pragma unroll
    for (int c = 0; c < 4; ++c)
#pragma unroll
      for (int e = 0; e < 8; ++e) mt = fmaxf(mt, (float)ch[c][e]);
    mt = fmaxf(mt, __shfl_xor(mt, 1));
    float mnew = fmaxf(m_run, mt);
    float resc = __expf(m_run - mnew);
    float lsum = 0.f;
#pragma unroll
    for (int c = 0; c < 4; ++c) {
      f16x8 p8;
#pragma unroll
      for (int e = 0; e < 8; ++e) {
        float p = __expf((float)ch[c][e] - mnew);
        lsum += p;
        p8[e] = (f16_t)p;
      }
      *(f16x8*)((char*)SP + myrow * 128 + ((half * 64 + c * 16) ^ ((myrow & 7) << 4))) = p8;
    }
    lsum += __shfl_xor(lsum, 1);
    l_run = l_run * resc + lsum;
    m_run = mnew;
    if (half == 0) rsb[myrow] = resc;
    __syncthreads();
    // rescale O accumulator, then PV
#pragma unroll
    for (int i = 0; i < 2; ++i) {
      float f0 = rsb[w * 32 + i * 16 + lhi * 4 + 0];
      float f1 = rsb[w * 32 + i * 16 + lhi * 4 + 1];
      float f2 = rsb[w * 32 + i * 16 + lhi * 4 + 2];
      float f3 = rsb[w * 32 + i * 16 + lhi * 4 + 3];
#pragma unroll
      for (int j = 0; j < 4; ++j) {
        oacc[i][j][0] *= f0;
        oacc[i][j][1] *= f1;
        oacc[i][j][2] *= f2;
        oacc[i][j][3] *= f3;
      }
    }
    __builtin_amdgcn_s_setprio(1);
#pragma unroll
    for (int kk = 0; kk < 2; ++kk) {
      f16x8 pa[2], vb[4];
#pragma unroll
      for (int i = 0; i < 2; ++i) {
        int row = w * 32 + i * 16 + l15;
        pa[i] = *(const f16x8*)((char*)SP + row * 128 +
                                ((kk * 64 + lhi * 16) ^ ((row & 7) << 4)));
      }
#pragma unroll
      for (int j = 0; j < 4; ++j) {
        int row = j * 16 + l15;
        vb[j] = *(const f16x8*)((char*)Vts + row * 128 +
                                ((kk * 64 + lhi * 16) ^ ((row & 7) << 4)));
      }
#pragma unroll
      for (int i = 0; i < 2; ++i)
#pragma unroll
        for (int j = 0; j < 4; ++j) oacc[i][j] = MFMA16(pa[i], vb[j], oacc[i][j]);
    }
    __builtin_amdgcn_s_setprio(0);
  }
  if (half == 0) lib[myrow] = 1.f / l_run;
  __syncthreads();
#pragma unroll
  for (int i = 0; i < 2; ++i)
#pragma unroll
    for (int r = 0; r < 4; ++r) {
      int row = w * 32 + i * 16 + lhi * 4 + r;
      float li = lib[row];
      size_t base = ((size_t)b * S + q0 + row) * D + h * 64;
#pragma unroll
      for (int j = 0; j < 4; ++j)
        wv[base + j * 16 + l15] = (f16_t)(oacc[i][j][r] * li);
    }
}

// ---------------------------------------------------------------------------
extern "C" void kernel_launch(void* const* d_in, const int* in_sizes, int n_in,
                              void* d_out, int out_size, void* d_ws, size_t ws_size,
                              hipStream_t stream) {
  const int B = 8, S = 1024, D = 1024, F = 4096;
  const int M = B * S;  // 8192

  const float* x = (const float*)d_in[0];
  const float* Wq = (const float*)d_in[1];
  const float* bq = (const float*)d_in[2];
  const float* Wk = (const float*)d_in[3];
  const float* Wv = (const float*)d_in[4];
  const float* bv = (const float*)d_in[5];
  const float* Wo = (const float*)d_in[6];
  const float* bo = (const float*)d_in[7];
  const float* la_k = (const float*)d_in[8];
  const float* lb_k = (const float*)d_in[9];
  const float* la_v = (const float*)d_in[10];
  const float* lb_v = (const float*)d_in[11];
  const float* la_o = (const float*)d_in[12];
  const float* lb_o = (const float*)d_in[13];
  const float* g_attn = (const float*)d_in[14];
  const float* b_attn = (const float*)d_in[15];
  const float* W1 = (const float*)d_in[16];
  const float* b1 = (const float*)d_in[17];
  const float* W2 = (const float*)d_in[18];
  const float* b2 = (const float*)d_in[19];
  const float* g_mlp = (const float*)d_in[20];
  const float* b_mlp = (const float*)d_in[21];

  // ---- workspace layout ----
  // [16B pad][t_k][t_v][t_o fp32, ~384KB] [P0][P1][P2][P3] (16 MiB each, f16)
  // [Wqkvf 3D*D][Wof D*D][W1f F*D][W2f D*F] f16 weights (24 MiB total).
  float* t_k = (float*)((char*)d_ws + 16);
  float* t_v = t_k + (size_t)M * 4;
  float* t_o = t_v + (size_t)M * 4;
  const size_t MD = (size_t)M * D;
  f16_t* P0 = (f16_t*)((char*)d_ws + 409600);
  f16_t* P1 = P0 + MD;
  f16_t* P2 = P0 + 2 * MD;
  f16_t* P3 = P0 + 3 * MD;
  f16_t* Wqkvf = P0 + 4 * MD;                  // [3072,1024] f16
  f16_t* Wof = Wqkvf + 3 * (size_t)D * D;
  f16_t* W1f = Wof + (size_t)D * D;
  f16_t* W2f = W1f + (size_t)F * D;
  float* outf = (float*)d_out;
  const size_t need = 409600 + 4 * MD * sizeof(f16_t) +
                      (4 * (size_t)D * D + 2 * (size_t)F * D) * sizeof(f16_t);
  const bool f16w = ws_size >= need;

  if (f16w)
    convert_w<<<6144, 256, 0, stream>>>(
        Wq, Wk, Wv, Wo, W1, W2, Wqkvf, Wqkvf + (size_t)D * D,
        Wqkvf + 2 * (size_t)D * D, Wof, W1f, W2f);

  // 1. h = LN(x) -> P0
  ln_f32<<<M, 256, 0, stream>>>(x, g_attn, b_attn, P0);
  // 2. LoRA t for k and v (one pass over h)
  lora_kv_kernel<<<M / 4, 256, 0, stream>>>(P0, la_k, la_v, t_k, t_v, D);
  // 3. fused QKV projection: q -> P1, k -> P2, v -> P3 ([B,H,64,S] transposed)
  if (f16w) {
    gemm_qkv_pipe<<<dim3(12, 64), 512, 0, stream>>>(
        P0, Wqkvf, bq, bv, t_k, lb_k, t_v, lb_v, P1, P2, P3, D);
  } else {
    gemm_mfma<<<dim3(8, 64), 256, 0, stream>>>(
        P0, Wq, bq, nullptr, nullptr, nullptr, nullptr, P1, nullptr, nullptr,
        M, D, D, D, 0);
    gemm_mfma<<<dim3(8, 64), 256, 0, stream>>>(
        P0, Wk, nullptr, t_k, lb_k, nullptr, nullptr, P2, nullptr, nullptr,
        M, D, D, D, 0);
    gemm_mfma<<<dim3(8, 64), 256, 0, stream>>>(
        P0, Wv, bv, t_v, lb_v, nullptr, nullptr, nullptr, nullptr, P3,
        M, D, D, D, 0);
  }
  // 4. attention -> wv (f16) -> P0 (h dead); proven 128-q-row blocks
  attn_mfma<<<dim3(8, 16, 8), 256, 0, stream>>>(P1, P2, P3, P0);
  // 5. LoRA t for o (input wv)
  lora_t_kernel<<<M / 4, 256, 0, stream>>>(P0, la_o, t_o, D);
  // 6. x1 = x + wv @ Wo^T + bo + lora_o -> P3 (f16; q/k/Vt dead)
  if (f16w)
    gemm_pipe<<<dim3(4, 64), 512, 0, stream>>>(
        P0, Wof, bo, t_o, lb_o, x, nullptr, P3, nullptr, M, D, D, D, 0);
  else
    gemm_mfma<<<dim3(8, 64), 256, 0, stream>>>(
        P0, Wo, bo, t_o, lb_o, x, nullptr, P3, nullptr, nullptr, M, D, D, D, 0);
  // 7. h2 = LN(x1) -> P0 (wv dead)
  ln_f16<<<M, 256, 0, stream>>>(P3, g_mlp, b_mlp, P0);
  // 8/9. MLP in two N=2048 halves: u -> P1∪P2, out accumulates on d_out (f32)
  if (f16w) {
    gemm_pipe<<<dim3(8, 64), 512, 0, stream>>>(
        P0, W1f, b1, nullptr, nullptr, nullptr, nullptr, P1, nullptr,
        M, 2048, D, D, 1);
    gemm_pipe<<<dim3(4, 64), 512, 0, stream>>>(
        P1, W2f, b2, nullptr, nullptr, nullptr, P3, nullptr, outf,
        M, D, 2048, F, 0);
    gemm_pipe<<<dim3(8, 64), 512, 0, stream>>>(
        P0, W1f + (size_t)2048 * D, b1 + 2048, nullptr, nullptr, nullptr, nullptr,
        P1, nullptr, M, 2048, D, D, 1);
    gemm_pipe<<<dim3(4, 64), 512, 0, stream>>>(
        P1, W2f + 2048, nullptr, nullptr, nullptr, outf, nullptr, nullptr, outf,
        M, D, 2048, F, 0);
  } else {
    gemm_mfma<<<dim3(16, 64), 256, 0, stream>>>(
        P0, W1, b1, nullptr, nullptr, nullptr, nullptr, P1, nullptr, nullptr,
        M, 2048, D, D, 1);
    gemm_mfma<<<dim3(8, 64), 256, 0, stream>>>(
        P1, W2, b2, nullptr, nullptr, nullptr, P3, nullptr, outf, nullptr,
        M, D, 2048, F, 0);
    gemm_mfma<<<dim3(16, 64), 256, 0, stream>>>(
        P0, W1 + (size_t)2048 * D, b1 + 2048, nullptr, nullptr, nullptr, nullptr,
        P1, nullptr, nullptr, M, 2048, D, D, 1);
    gemm_mfma<<<dim3(8, 64), 256, 0, stream>>>(
        P1, W2 + 2048, nullptr, nullptr, nullptr, outf, nullptr, nullptr, outf,
        nullptr, M, D, 2048, F, 0);
  }
}